// Round 13
// baseline (661.027 us; speedup 1.0000x reference)
//
#include <hip/hip_runtime.h>

#define NN 60000
#define NE 180000
#define NG 2048
#define NL 5
#define CAP 32

typedef unsigned short u16;
typedef unsigned int u32;
typedef __bf16 bf16x8 __attribute__((ext_vector_type(8)));
typedef float f32x4 __attribute__((ext_vector_type(4)));

__device__ __forceinline__ u16 f2bf(float f) {
    u32 u = __builtin_bit_cast(u32, f);
    u += 0x7FFFu + ((u >> 16) & 1u);
    return (u16)(u >> 16);
}
__device__ __forceinline__ float bf2f(u16 s) {
    return __builtin_bit_cast(float, (u32)s << 16);
}
__device__ __forceinline__ float bflo(u32 w) {
    return __builtin_bit_cast(float, w << 16);
}
__device__ __forceinline__ float bfhi(u32 w) {
    return __builtin_bit_cast(float, w & 0xFFFF0000u);
}
__device__ __forceinline__ u32 pack2bf(float lo, float hi) {
    return (u32)f2bf(lo) | ((u32)f2bf(hi) << 16);
}
__device__ __forceinline__ void gload_lds16(const void* g, void* l) {
    __builtin_amdgcn_global_load_lds(
        (const __attribute__((address_space(1))) unsigned int*)g,
        (__attribute__((address_space(3))) unsigned int*)l, 16, 0, 0);
}
// swizzled byte offset into a [rows][256] bf16 LDS tile (chunk ^= row&7, low 3 bits)
__device__ __forceinline__ int swz(int row, int col) {
    return (row << 9) + ((((col >> 3) ^ (row & 7))) << 4) + ((col & 7) << 1);
}

__constant__ int NODE_OFF[9]  = {0, 119, 124, 136, 148, 158, 164, 170, 172};
__constant__ int NODE_MAXC[9] = {118, 4, 11, 11, 9, 5, 5, 1, 1};

// ---- transpose + bf16-cast the 21 256x256 weight matrices ----
__global__ __launch_bounds__(256) void k_prep_weights(
    const float* __restrict__ W1, const float* __restrict__ W2,
    const float* __restrict__ vW1, const float* __restrict__ vW2,
    const float* __restrict__ hW1, u16* __restrict__ Wt)
{
    int mat = blockIdx.x >> 8;
    int n = blockIdx.x & 255;
    int k = threadIdx.x;
    const float* src;
    if (mat < 5)       src = W1 + (size_t)mat * 65536;
    else if (mat < 10) src = W2 + (size_t)(mat - 5) * 65536;
    else if (mat < 15) src = vW1 + (size_t)(mat - 10) * 65536;
    else if (mat < 20) src = vW2 + (size_t)(mat - 15) * 65536;
    else               src = hW1;
    Wt[(size_t)mat * 65536 + n * 256 + k] = f2bf(src[k * 256 + n]);
}

// ---- fused setup: vn init + gsum zero | comb table | segment starts ----
__global__ __launch_bounds__(256) void k_misc(
    const float* __restrict__ eemb, const int* __restrict__ batch,
    const float* __restrict__ vn_emb,
    u16* __restrict__ comb, int* __restrict__ starts,
    float* __restrict__ vn, u16* __restrict__ vnbf, float* __restrict__ gsum)
{
    int b = blockIdx.x;
    if (b < 2048) {
        int i = b * 256 + threadIdx.x;
        float v = vn_emb[i & 255];
        vn[i] = v;
        vnbf[i] = f2bf(v);
        gsum[i] = 0.f;
    } else if (b < 2108) {
        int r = b - 2048, c = threadIdx.x;
        int a0 = r / 12, a1 = (r % 12) / 2, a2 = r & 1;
        comb[r * 256 + c] = f2bf(eemb[a0 * 256 + c] + eemb[(5 + a1) * 256 + c] +
                                 eemb[(11 + a2) * 256 + c]);
    } else {
        int g = (b - 2108) * 256 + threadIdx.x;
        if (g > NG) return;
        int lo = 0, hi = NN;
        while (lo < hi) {
            int mid = (lo + hi) >> 1;
            if (batch[mid] < g) lo = mid + 1; else hi = mid;
        }
        starts[g] = lo;
    }
}

// ---- node embedding -> bf16 h; also zero deg ----
__global__ __launch_bounds__(256) void k_embed(const int* __restrict__ x,
                                               const float* __restrict__ node_emb,
                                               u16* __restrict__ hbf,
                                               int* __restrict__ deg)
{
    int i = blockIdx.x * 4 + (threadIdx.x >> 6);
    if (i >= NN) return;
    if ((threadIdx.x & 63) == 0) deg[i] = 0;
    int c = (threadIdx.x & 63) * 4;
    float4 s = make_float4(0.f, 0.f, 0.f, 0.f);
#pragma unroll
    for (int f = 0; f < 9; ++f) {
        int xv = x[i * 9 + f];
        xv = xv < 0 ? 0 : (xv > NODE_MAXC[f] ? NODE_MAXC[f] : xv);
        const float4 t = *(const float4*)&node_emb[(size_t)(NODE_OFF[f] + xv) * 256 + c];
        s.x += t.x; s.y += t.y; s.z += t.z; s.w += t.w;
    }
    ushort4 o;
    o.x = f2bf(s.x); o.y = f2bf(s.y); o.z = f2bf(s.z); o.w = f2bf(s.w);
    *(ushort4*)&hbf[(size_t)i * 256 + c] = o;
}

// ---- CSR-bucket build: slots[d*CAP+p] = src | code<<17 ----
__global__ __launch_bounds__(256) void k_bucket(
    const int* __restrict__ src, const int* __restrict__ dst,
    const int* __restrict__ eattr, int* __restrict__ deg, u32* __restrict__ slots)
{
    int e = blockIdx.x * 256 + threadIdx.x;
    if (e >= NE) return;
    int a0 = eattr[e * 3 + 0]; a0 = a0 < 0 ? 0 : (a0 > 4 ? 4 : a0);
    int a1 = eattr[e * 3 + 1]; a1 = a1 < 0 ? 0 : (a1 > 5 ? 5 : a1);
    int a2 = eattr[e * 3 + 2]; a2 = a2 < 0 ? 0 : (a2 > 1 ? 1 : a2);
    u32 code = (u32)(a0 * 12 + a1 * 2 + a2);
    int d = dst[e];
    int p = atomicAdd(&deg[d], 1);
    if (p < CAP) slots[(size_t)d * CAP + p] = (u32)src[e] | (code << 17);
}

// ---- gather-aggregate: one node per 32-lane HALF-wave (ILP-2 per wave) ----
__global__ __launch_bounds__(256) void k_agg(
    const u16* __restrict__ hbf, const u16* __restrict__ vnbf,
    const int* __restrict__ batch, const u32* __restrict__ slots,
    const int* __restrict__ deg, const u16* __restrict__ comb,
    u16* __restrict__ Abf, const float* __restrict__ epsp)
{
    const int wid = threadIdx.x >> 6, lane = threadIdx.x & 63;
    const int half = lane >> 5, l32 = lane & 31;
    const int d = blockIdx.x * 8 + wid * 2 + half;
    const int c = l32 * 8;
    int nd = deg[d];
    nd = nd > CAP ? CAP : nd;

    const u32* sl = slots + (size_t)d * CAP;
    u32 sv_l = (l32 < nd) ? sl[l32] : 0u;
    int b_l = (l32 < nd) ? batch[sv_l & 0x1FFFFu] : 0;

    float acc[8] = {0.f, 0.f, 0.f, 0.f, 0.f, 0.f, 0.f, 0.f};
    for (int p = 0; p < nd; ++p) {
        int srcl = (lane & 32) | p;
        u32 sv = (u32)__shfl((int)sv_l, srcl);
        int b  = __shfl(b_l, srcl);
        int s  = (int)(sv & 0x1FFFFu);
        int code = (int)(sv >> 17);
        const uint4 hv = *(const uint4*)&hbf[(size_t)s * 256 + c];
        const uint4 vv = *(const uint4*)&vnbf[(size_t)b * 256 + c];
        const uint4 tv = *(const uint4*)&comb[(size_t)code * 256 + c];
        const u32* hw = (const u32*)&hv;
        const u32* vw = (const u32*)&vv;
        const u32* tw = (const u32*)&tv;
#pragma unroll
        for (int e = 0; e < 4; ++e) {
            acc[e * 2 + 0] += fmaxf(bflo(hw[e]) + bflo(vw[e]) + bflo(tw[e]), 0.f);
            acc[e * 2 + 1] += fmaxf(bfhi(hw[e]) + bfhi(vw[e]) + bfhi(tw[e]), 0.f);
        }
    }

    int bd = batch[d];
    float ep = 1.0f + *epsp;
    const uint4 hd = *(const uint4*)&hbf[(size_t)d * 256 + c];
    const uint4 vd = *(const uint4*)&vnbf[(size_t)bd * 256 + c];
    const u32* hw = (const u32*)&hd;
    const u32* vw = (const u32*)&vd;
    uint4 o;
    u32* op = (u32*)&o;
#pragma unroll
    for (int e = 0; e < 4; ++e) {
        float lo = (bflo(hw[e]) + bflo(vw[e])) * ep + acc[e * 2 + 0];
        float hi = (bfhi(hw[e]) + bfhi(vw[e])) * ep + acc[e * 2 + 1];
        op[e] = pack2bf(lo, hi);
    }
    *(uint4*)&Abf[(size_t)d * 256 + c] = o;
}

// ======== shared GEMM building blocks (64-row tile, 8 waves) ========
__device__ __forceinline__ void stageW(const u16* __restrict__ W, u16* Bl,
                                       int k0, int tid, int wid)
{
#pragma unroll
    for (int i = 0; i < 4; ++i) {
        int slot = i * 512 + tid;
        int row = slot >> 3, cch = slot & 7;
        int g = cch ^ (row & 7);
        gload_lds16((const char*)W + (size_t)row * 512 + (size_t)k0 * 2 + (g << 4),
                    (char*)Bl + ((i * 512 + wid * 64) << 4));
    }
}

__device__ __forceinline__ void gemm64(const u16* Tl, u16* Bl, const u16* __restrict__ W,
                                       f32x4 (&acc)[2][4], int wm, int wn,
                                       int lane, int tid, int wid)
{
    const int cl = lane & 15;
    for (int k0 = 0; k0 < 256; k0 += 64) {
        __syncthreads();
        stageW(W, Bl, k0, tid, wid);
        __syncthreads();
#pragma unroll
        for (int kw = 0; kw < 2; ++kw) {
            int q = kw * 4 + (lane >> 4);
            int qt = (k0 >> 3) + q;
            bf16x8 af[2], bfr[4];
#pragma unroll
            for (int t = 0; t < 2; ++t) {
                int ar = wm + t * 16 + cl;
                af[t] = __builtin_bit_cast(bf16x8,
                    *(const uint4*)((const char*)Tl + (ar << 9) + ((qt ^ (ar & 7)) << 4)));
            }
#pragma unroll
            for (int t = 0; t < 4; ++t) {
                int br = wn + t * 16 + cl;
                bfr[t] = __builtin_bit_cast(bf16x8,
                    *(const uint4*)((const char*)Bl + (br << 7) + ((q ^ (br & 7)) << 4)));
            }
#pragma unroll
            for (int i = 0; i < 2; ++i)
#pragma unroll
                for (int j = 0; j < 4; ++j)
                    acc[i][j] = __builtin_amdgcn_mfma_f32_16x16x32_bf16(af[i], bfr[j], acc[i][j], 0, 0, 0);
        }
    }
}

__device__ __forceinline__ void writeT(u16* Tl, const f32x4 (&acc)[2][4],
                                       const float* __restrict__ b1,
                                       int wm, int wn, int lane)
{
    const int cl = lane & 15, rg = lane >> 4;
#pragma unroll
    for (int j = 0; j < 4; ++j) {
        int col = wn + j * 16 + cl;
        float bv = b1[col];
#pragma unroll
        for (int i = 0; i < 2; ++i)
#pragma unroll
            for (int r = 0; r < 4; ++r) {
                int row = wm + i * 16 + rg * 4 + r;
                float v = fmaxf(acc[i][j][r] + bv, 0.f);
                *(u16*)((char*)Tl + swz(row, col)) = f2bf(v);
            }
    }
}

// ======== VARIANT A: r6 k_mlpP — W staged through LDS, BK=64 (control, ~49µs) ========
__global__ __launch_bounds__(512) void k_mlpP(
    const u16* __restrict__ Abf, u16* __restrict__ hnxt,
    const int* __restrict__ batch,
    const u16* __restrict__ W1t, const u16* __restrict__ W2t,
    const float* __restrict__ b1, const float* __restrict__ b2,
    const float* __restrict__ bng, const float* __restrict__ bnb,
    const float* __restrict__ bnm, const float* __restrict__ bnv,
    float* __restrict__ gsum)
{
    __shared__ __align__(16) u16 Bl[256 * 64];
    __shared__ __align__(16) u16 Tl[64 * 256];
    __shared__ int batchLds[64];
    const int m0 = blockIdx.x * 64;
    const int tid = threadIdx.x, lane = tid & 63, wid = tid >> 6;
    const int wm = (wid >> 2) * 32, wn = (wid & 3) * 64;
    const int cl = lane & 15, rg = lane >> 4;

    if (tid < 64) batchLds[tid] = (m0 + tid < NN) ? batch[m0 + tid] : -1;

#pragma unroll
    for (int i = 0; i < 4; ++i) {
        int slot = i * 512 + tid;
        int row = slot >> 5, cch = slot & 31;
        int g = cch ^ (row & 7);
        gload_lds16((const char*)Abf + (size_t)(m0 + row) * 512 + (g << 4),
                    (char*)Tl + ((i * 512 + wid * 64) << 4));
    }

    f32x4 acc1[2][4] = {};
    gemm64(Tl, Bl, W1t, acc1, wm, wn, lane, tid, wid);
    __syncthreads();
    writeT(Tl, acc1, b1, wm, wn, lane);

    f32x4 acc2[2][4] = {};
    gemm64(Tl, Bl, W2t, acc2, wm, wn, lane, tid, wid);
    __syncthreads();

#pragma unroll
    for (int j = 0; j < 4; ++j) {
        int gn = wn + j * 16 + cl;
        float bv = b2[gn];
        float sc = bng[gn] * rsqrtf(bnv[gn] + 1e-5f);
        float sh = bnb[gn] - bnm[gn] * sc;
        float s = 0.f;
        int gcur = -1;
#pragma unroll
        for (int i = 0; i < 2; ++i) {
#pragma unroll
            for (int r = 0; r < 4; ++r) {
                int row = wm + i * 16 + rg * 4 + r;
                int g = batchLds[row];
                float v = acc2[i][j][r] + bv;
                u16 hb = f2bf(fmaxf(v * sc + sh, 0.f));
                if (g >= 0) hnxt[(size_t)(m0 + row) * 256 + gn] = hb;
                if (g != gcur) {
                    if (gcur >= 0) atomicAdd(&gsum[(size_t)gcur * 256 + gn], s);
                    gcur = g; s = 0.f;
                }
                if (g >= 0) s += bf2f(hb);
            }
        }
        if (gcur >= 0) atomicAdd(&gsum[(size_t)gcur * 256 + gn], s);
    }
}

// ======== VARIANT B/C: k_mlpD — W direct from L2, no W-LDS, 3 barriers total ========
template <int POOL>
__global__ __launch_bounds__(512) void k_mlpD(
    const u16* __restrict__ Abf, u16* __restrict__ hnxt,
    const int* __restrict__ batch,
    const u16* __restrict__ W1t, const u16* __restrict__ W2t,
    const float* __restrict__ b1, const float* __restrict__ b2,
    const float* __restrict__ bng, const float* __restrict__ bnb,
    const float* __restrict__ bnm, const float* __restrict__ bnv,
    float* __restrict__ gsum)
{
    __shared__ __align__(16) u16 Tl[64 * 256];
    __shared__ int batchLds[64];
    const int m0 = blockIdx.x * 64;
    const int tid = threadIdx.x, lane = tid & 63, wid = tid >> 6;
    const int wm = (wid >> 2) * 32, wn = (wid & 3) * 64;
    const int cl = lane & 15, rg = lane >> 4;

    if (tid < 64) batchLds[tid] = (m0 + tid < NN) ? batch[m0 + tid] : -1;

#pragma unroll
    for (int i = 0; i < 4; ++i) {
        int slot = i * 512 + tid;
        int row = slot >> 5, cch = slot & 31;
        int g = cch ^ (row & 7);
        gload_lds16((const char*)Abf + (size_t)(m0 + row) * 512 + (g << 4),
                    (char*)Tl + ((i * 512 + wid * 64) << 4));
    }
    __syncthreads();

    f32x4 acc1[2][4] = {};
#pragma unroll
    for (int p = 0; p < 8; ++p) {
        int ch = p * 4 + rg;
        bf16x8 af[2], bfr[4];
#pragma unroll
        for (int t = 0; t < 2; ++t) {
            int ar = wm + t * 16 + cl;
            af[t] = __builtin_bit_cast(bf16x8,
                *(const uint4*)((const char*)Tl + (ar << 9) + ((ch ^ (ar & 7)) << 4)));
        }
#pragma unroll
        for (int u = 0; u < 4; ++u) {
            int br = wn + u * 16 + cl;
            bfr[u] = __builtin_bit_cast(bf16x8,
                *(const uint4*)((const char*)W1t + (size_t)br * 512 + (ch << 4)));
        }
#pragma unroll
        for (int t = 0; t < 2; ++t)
#pragma unroll
            for (int u = 0; u < 4; ++u)
                acc1[t][u] = __builtin_amdgcn_mfma_f32_16x16x32_bf16(af[t], bfr[u], acc1[t][u], 0, 0, 0);
    }
    __syncthreads();
    writeT(Tl, acc1, b1, wm, wn, lane);
    __syncthreads();

    f32x4 acc2[2][4] = {};
#pragma unroll
    for (int p = 0; p < 8; ++p) {
        int ch = p * 4 + rg;
        bf16x8 af[2], bfr[4];
#pragma unroll
        for (int t = 0; t < 2; ++t) {
            int ar = wm + t * 16 + cl;
            af[t] = __builtin_bit_cast(bf16x8,
                *(const uint4*)((const char*)Tl + (ar << 9) + ((ch ^ (ar & 7)) << 4)));
        }
#pragma unroll
        for (int u = 0; u < 4; ++u) {
            int br = wn + u * 16 + cl;
            bfr[u] = __builtin_bit_cast(bf16x8,
                *(const uint4*)((const char*)W2t + (size_t)br * 512 + (ch << 4)));
        }
#pragma unroll
        for (int t = 0; t < 2; ++t)
#pragma unroll
            for (int u = 0; u < 4; ++u)
                acc2[t][u] = __builtin_amdgcn_mfma_f32_16x16x32_bf16(af[t], bfr[u], acc2[t][u], 0, 0, 0);
    }

#pragma unroll
    for (int j = 0; j < 4; ++j) {
        int gn = wn + j * 16 + cl;
        float bv = b2[gn];
        float sc = bng[gn] * rsqrtf(bnv[gn] + 1e-5f);
        float sh = bnb[gn] - bnm[gn] * sc;
        float s = 0.f;
        int gcur = -1;
#pragma unroll
        for (int i = 0; i < 2; ++i) {
#pragma unroll
            for (int r = 0; r < 4; ++r) {
                int row = wm + i * 16 + rg * 4 + r;
                int g = batchLds[row];
                float v = acc2[i][j][r] + bv;
                u16 hb = f2bf(fmaxf(v * sc + sh, 0.f));
                if (g >= 0) hnxt[(size_t)(m0 + row) * 256 + gn] = hb;
                if constexpr (POOL) {
                    if (g != gcur) {
                        if (gcur >= 0) atomicAdd(&gsum[(size_t)gcur * 256 + gn], s);
                        gcur = g; s = 0.f;
                    }
                    if (g >= 0) s += bf2f(hb);
                }
            }
        }
        if constexpr (POOL) {
            if (gcur >= 0) atomicAdd(&gsum[(size_t)gcur * 256 + gn], s);
        }
    }
}

// ---- standalone pool (for the no-pool variant's layer) ----
__global__ __launch_bounds__(256) void k_poolB(const u16* __restrict__ h,
                                               const int* __restrict__ batch,
                                               float* __restrict__ gsum)
{
    __shared__ int bl[64];
    int r0 = blockIdx.x * 64;
    if (threadIdx.x < 64) bl[threadIdx.x] = (r0 + threadIdx.x < NN) ? batch[r0 + threadIdx.x] : -1;
    __syncthreads();
    int col = threadIdx.x;
    float s = 0.f;
    int gcur = -1;
    for (int r = 0; r < 64; ++r) {
        int g = bl[r];
        if (g < 0) break;
        if (g != gcur) {
            if (gcur >= 0) atomicAdd(&gsum[(size_t)gcur * 256 + col], s);
            gcur = g; s = 0.f;
        }
        s += bf2f(h[(size_t)(r0 + r) * 256 + col]);
    }
    if (gcur >= 0) atomicAdd(&gsum[(size_t)gcur * 256 + col], s);
}

// ======== VARIANT D: k_mlpD128 — direct-W, BM=128 (half the blocks, 2x A-reuse) ========
__global__ __launch_bounds__(512) void k_mlpD128(
    const u16* __restrict__ Abf, u16* __restrict__ hnxt,
    const int* __restrict__ batch,
    const u16* __restrict__ W1t, const u16* __restrict__ W2t,
    const float* __restrict__ b1, const float* __restrict__ b2,
    const float* __restrict__ bng, const float* __restrict__ bnb,
    const float* __restrict__ bnm, const float* __restrict__ bnv,
    float* __restrict__ gsum)
{
    __shared__ __align__(16) u16 Tl[128 * 256];   // 64 KB
    __shared__ int batchLds[128];
    const int m0 = blockIdx.x * 128;
    const int tid = threadIdx.x, lane = tid & 63, wid = tid >> 6;
    const int wm = (wid >> 2) * 64, wn = (wid & 3) * 64;
    const int cl = lane & 15, rg = lane >> 4;

    if (tid < 128) batchLds[tid] = (m0 + tid < NN) ? batch[m0 + tid] : -1;

#pragma unroll
    for (int i = 0; i < 8; ++i) {
        int slot = i * 512 + tid;
        int row = slot >> 5, cch = slot & 31;
        int g = cch ^ (row & 7);
        gload_lds16((const char*)Abf + (size_t)(m0 + row) * 512 + (g << 4),
                    (char*)Tl + ((i * 512 + wid * 64) << 4));
    }
    __syncthreads();

    f32x4 acc1[4][4] = {};
#pragma unroll
    for (int p = 0; p < 8; ++p) {
        int ch = p * 4 + rg;
        bf16x8 af[4], bfr[4];
#pragma unroll
        for (int t = 0; t < 4; ++t) {
            int ar = wm + t * 16 + cl;
            af[t] = __builtin_bit_cast(bf16x8,
                *(const uint4*)((const char*)Tl + (ar << 9) + ((ch ^ (ar & 7)) << 4)));
        }
#pragma unroll
        for (int u = 0; u < 4; ++u) {
            int br = wn + u * 16 + cl;
            bfr[u] = __builtin_bit_cast(bf16x8,
                *(const uint4*)((const char*)W1t + (size_t)br * 512 + (ch << 4)));
        }
#pragma unroll
        for (int t = 0; t < 4; ++t)
#pragma unroll
            for (int u = 0; u < 4; ++u)
                acc1[t][u] = __builtin_amdgcn_mfma_f32_16x16x32_bf16(af[t], bfr[u], acc1[t][u], 0, 0, 0);
    }
    __syncthreads();
    // T write (4 row-tiles)
#pragma unroll
    for (int j = 0; j < 4; ++j) {
        int col = wn + j * 16 + cl;
        float bv = b1[col];
#pragma unroll
        for (int i = 0; i < 4; ++i)
#pragma unroll
            for (int r = 0; r < 4; ++r) {
                int row = wm + i * 16 + rg * 4 + r;
                float v = fmaxf(acc1[i][j][r] + bv, 0.f);
                *(u16*)((char*)Tl + swz(row, col)) = f2bf(v);
            }
    }
    __syncthreads();

    f32x4 acc2[4][4] = {};
#pragma unroll
    for (int p = 0; p < 8; ++p) {
        int ch = p * 4 + rg;
        bf16x8 af[4], bfr[4];
#pragma unroll
        for (int t = 0; t < 4; ++t) {
            int ar = wm + t * 16 + cl;
            af[t] = __builtin_bit_cast(bf16x8,
                *(const uint4*)((const char*)Tl + (ar << 9) + ((ch ^ (ar & 7)) << 4)));
        }
#pragma unroll
        for (int u = 0; u < 4; ++u) {
            int br = wn + u * 16 + cl;
            bfr[u] = __builtin_bit_cast(bf16x8,
                *(const uint4*)((const char*)W2t + (size_t)br * 512 + (ch << 4)));
        }
#pragma unroll
        for (int t = 0; t < 4; ++t)
#pragma unroll
            for (int u = 0; u < 4; ++u)
                acc2[t][u] = __builtin_amdgcn_mfma_f32_16x16x32_bf16(af[t], bfr[u], acc2[t][u], 0, 0, 0);
    }

#pragma unroll
    for (int j = 0; j < 4; ++j) {
        int gn = wn + j * 16 + cl;
        float bv = b2[gn];
        float sc = bng[gn] * rsqrtf(bnv[gn] + 1e-5f);
        float sh = bnb[gn] - bnm[gn] * sc;
        float s = 0.f;
        int gcur = -1;
#pragma unroll
        for (int i = 0; i < 4; ++i) {
#pragma unroll
            for (int r = 0; r < 4; ++r) {
                int row = wm + i * 16 + rg * 4 + r;
                int g = batchLds[row];
                float v = acc2[i][j][r] + bv;
                u16 hb = f2bf(fmaxf(v * sc + sh, 0.f));
                if (g >= 0) hnxt[(size_t)(m0 + row) * 256 + gn] = hb;
                if (g != gcur) {
                    if (gcur >= 0) atomicAdd(&gsum[(size_t)gcur * 256 + gn], s);
                    gcur = g; s = 0.f;
                }
                if (g >= 0) s += bf2f(hb);
            }
        }
        if (gcur >= 0) atomicAdd(&gsum[(size_t)gcur * 256 + gn], s);
    }
}

// ======== fused pool-normalize + vn MLP (32 blocks x 64 graphs) ========
__global__ __launch_bounds__(512) void k_vnmlp(
    float* __restrict__ gsum, const int* __restrict__ starts,
    const u16* __restrict__ W1t, const u16* __restrict__ W2t,
    const float* __restrict__ b1, const float* __restrict__ b2,
    float* __restrict__ vn, u16* __restrict__ vnbf)
{
    __shared__ __align__(16) u16 Bl[256 * 64];
    __shared__ __align__(16) u16 Tl[64 * 256];
    const int m0 = blockIdx.x * 64;
    const int tid = threadIdx.x, lane = tid & 63, wid = tid >> 6;
    const int wm = (wid >> 2) * 32, wn = (wid & 3) * 64;
    const int cl = lane & 15, rg = lane >> 4;

    {
        const int c = lane * 4;
#pragma unroll
        for (int n = 0; n < 8; ++n) {
            int row = wid * 8 + n;
            int g = m0 + row;
            float4 sv = *(const float4*)&gsum[(size_t)g * 256 + c];
            *(float4*)&gsum[(size_t)g * 256 + c] = make_float4(0.f, 0.f, 0.f, 0.f);
            float cnt = (float)(starts[g + 1] - starts[g]);
            float inv = 1.0f / fmaxf(cnt, 1.0f);
            ushort4 o;
            o.x = f2bf(sv.x * inv); o.y = f2bf(sv.y * inv);
            o.z = f2bf(sv.z * inv); o.w = f2bf(sv.w * inv);
            *(ushort4*)((char*)Tl + swz(row, c)) = o;
        }
    }
    __syncthreads();

    f32x4 acc1[2][4] = {};
    gemm64(Tl, Bl, W1t, acc1, wm, wn, lane, tid, wid);
    __syncthreads();
    writeT(Tl, acc1, b1, wm, wn, lane);

    f32x4 acc2[2][4] = {};
    gemm64(Tl, Bl, W2t, acc2, wm, wn, lane, tid, wid);

#pragma unroll
    for (int j = 0; j < 4; ++j) {
        int gn = wn + j * 16 + cl;
        float bv = b2[gn];
#pragma unroll
        for (int i = 0; i < 2; ++i) {
#pragma unroll
            for (int r = 0; r < 4; ++r) {
                int gm = m0 + wm + i * 16 + rg * 4 + r;
                size_t idx = (size_t)gm * 256 + gn;
                float nv = vn[idx] + acc2[i][j][r] + bv;
                vn[idx] = nv;
                vnbf[idx] = f2bf(nv);
            }
        }
    }
}

// ======== fused head: pool-normalize -> relu(.@hW1+hb1) -> matvec hW2 ========
__global__ __launch_bounds__(512) void k_headf(
    const float* __restrict__ gsum, const int* __restrict__ starts,
    const u16* __restrict__ W1t, const float* __restrict__ b1,
    const float* __restrict__ hW2, const float* __restrict__ hb2,
    float* __restrict__ out)
{
    __shared__ __align__(16) u16 Bl[256 * 64];
    __shared__ __align__(16) u16 Tl[64 * 256];
    const int m0 = blockIdx.x * 64;
    const int tid = threadIdx.x, lane = tid & 63, wid = tid >> 6;
    const int wm = (wid >> 2) * 32, wn = (wid & 3) * 64;

    {
        const int c = lane * 4;
#pragma unroll
        for (int n = 0; n < 8; ++n) {
            int row = wid * 8 + n;
            int g = m0 + row;
            float4 sv = *(const float4*)&gsum[(size_t)g * 256 + c];
            float cnt = (float)(starts[g + 1] - starts[g]);
            float inv = 1.0f / fmaxf(cnt, 1.0f);
            ushort4 o;
            o.x = f2bf(sv.x * inv); o.y = f2bf(sv.y * inv);
            o.z = f2bf(sv.z * inv); o.w = f2bf(sv.w * inv);
            *(ushort4*)((char*)Tl + swz(row, c)) = o;
        }
    }
    __syncthreads();

    f32x4 acc1[2][4] = {};
    gemm64(Tl, Bl, W1t, acc1, wm, wn, lane, tid, wid);
    __syncthreads();
    writeT(Tl, acc1, b1, wm, wn, lane);
    __syncthreads();

    int row = tid >> 3, oct = tid & 7;
    float s = 0.f;
#pragma unroll
    for (int c = 0; c < 32; ++c) {
        int col = oct * 32 + c;
        s += bf2f(*(const u16*)((const char*)Tl + swz(row, col))) * hW2[col];
    }
    s += __shfl_down(s, 4);
    s += __shfl_down(s, 2);
    s += __shfl_down(s, 1);
    if (oct == 0) out[m0 + row] = s + hb2[0];
}

extern "C" void kernel_launch(void* const* d_in, const int* in_sizes, int n_in,
                              void* d_out, int out_size, void* d_ws, size_t ws_size,
                              hipStream_t stream)
{
    const int*   x        = (const int*)d_in[0];
    const int*   ei       = (const int*)d_in[1];
    const int*   eattr    = (const int*)d_in[2];
    const int*   batch    = (const int*)d_in[3];
    const float* node_emb = (const float*)d_in[4];
    const float* edge_emb = (const float*)d_in[5];
    const float* vn_emb   = (const float*)d_in[6];
    const float* eps      = (const float*)d_in[7];
    const float* W1       = (const float*)d_in[8];
    const float* b1       = (const float*)d_in[9];
    const float* W2       = (const float*)d_in[10];
    const float* b2       = (const float*)d_in[11];
    const float* bng      = (const float*)d_in[12];
    const float* bnb      = (const float*)d_in[13];
    const float* bnm      = (const float*)d_in[14];
    const float* bnv      = (const float*)d_in[15];
    const float* vW1      = (const float*)d_in[16];
    const float* vb1      = (const float*)d_in[17];
    const float* vW2      = (const float*)d_in[18];
    const float* vb2      = (const float*)d_in[19];
    const float* hW1      = (const float*)d_in[20];
    const float* hb1      = (const float*)d_in[21];
    const float* hW2      = (const float*)d_in[22];
    const float* hb2      = (const float*)d_in[23];
    float* out = (float*)d_out;

    char* ws = (char*)d_ws;
    size_t off = 0;
    auto alloc = [&](size_t b) {
        char* p = ws + off;
        off = (off + b + 255) & ~(size_t)255;
        return p;
    };
    u16*   hbf0 = (u16*)alloc((size_t)NN * 256 * 2);
    u16*   hbf1 = (u16*)alloc((size_t)NN * 256 * 2);
    u16*   Abf  = (u16*)alloc((size_t)NN * 256 * 2 + 65536);  // +64KB tail slack
    float* vn   = (float*)alloc((size_t)NG * 256 * 4);
    u16*   vnbf = (u16*)alloc((size_t)NG * 256 * 2);
    float* gsum = (float*)alloc((size_t)NG * 256 * 4);
    u16*   Wt   = (u16*)alloc((size_t)21 * 65536 * 2);
    int*   starts = (int*)alloc((size_t)(NG + 1) * 4);
    u16*   comb = (u16*)alloc((size_t)60 * 256 * 2);
    int*   deg  = (int*)alloc((size_t)NN * 4);
    u32*   slots = (u32*)alloc((size_t)NN * CAP * 4);

    const int* srcI = ei;
    const int* dstI = ei + NE;

    k_prep_weights<<<21 * 256, 256, 0, stream>>>(W1, W2, vW1, vW2, hW1, Wt);
    k_misc<<<2117, 256, 0, stream>>>(edge_emb, batch, vn_emb, comb, starts, vn, vnbf, gsum);
    k_embed<<<NN / 4, 256, 0, stream>>>(x, node_emb, hbf0, deg);
    k_bucket<<<(NE + 255) / 256, 256, 0, stream>>>(srcI, dstI, eattr, deg, slots);

    const int GBIG = (NN + 63) / 64;    // 938 blocks
    const int G128 = (NN + 127) / 128;  // 469 blocks
    const int GSM  = NG / 64;           // 32 blocks

    u16* hcur = hbf0;
    u16* hnxt = hbf1;
    for (int l = 0; l < NL; ++l) {
        k_agg<<<NN / 8, 256, 0, stream>>>(hcur, vnbf, batch, slots, deg, comb, Abf, eps + l);
        const u16* w1p = Wt + (size_t)(0 + l) * 65536;
        const u16* w2p = Wt + (size_t)(5 + l) * 65536;
        const float* b1p = b1 + l * 256;
        const float* b2p = b2 + l * 256;
        const float* gp = bng + l * 256;
        const float* bp = bnb + l * 256;
        const float* mp = bnm + l * 256;
        const float* vp = bnv + l * 256;
        if (l == 0) {
            k_mlpP<<<GBIG, 512, 0, stream>>>(Abf, hnxt, batch, w1p, w2p, b1p, b2p,
                                             gp, bp, mp, vp, gsum);
        } else if (l == 1 || l == 4) {
            k_mlpD<1><<<GBIG, 512, 0, stream>>>(Abf, hnxt, batch, w1p, w2p, b1p, b2p,
                                                gp, bp, mp, vp, gsum);
        } else if (l == 2) {
            k_mlpD<0><<<GBIG, 512, 0, stream>>>(Abf, hnxt, batch, w1p, w2p, b1p, b2p,
                                                gp, bp, mp, vp, gsum);
            k_poolB<<<GBIG, 256, 0, stream>>>(hnxt, batch, gsum);
        } else {  // l == 3
            k_mlpD128<<<G128, 512, 0, stream>>>(Abf, hnxt, batch, w1p, w2p, b1p, b2p,
                                                gp, bp, mp, vp, gsum);
        }
        if (l < NL - 1) {
            k_vnmlp<<<GSM, 512, 0, stream>>>(gsum, starts,
                                             Wt + (size_t)(10 + l) * 65536,
                                             Wt + (size_t)(15 + l) * 65536,
                                             vb1 + l * 256, vb2 + l * 256,
                                             vn, vnbf);
        }
        u16* t = hcur; hcur = hnxt; hnxt = t;
    }
    k_headf<<<GSM, 512, 0, stream>>>(gsum, starts, Wt + (size_t)20 * 65536,
                                     hb1, hW2, hb2, out);
}

// Round 14
// 601.860 us; speedup vs baseline: 1.0983x; 1.0983x over previous
//
#include <hip/hip_runtime.h>

#define NN 60000
#define NE 180000
#define NG 2048
#define NL 5
#define CAP 32

typedef unsigned short u16;
typedef unsigned int u32;
typedef __bf16 bf16x8 __attribute__((ext_vector_type(8)));
typedef float f32x4 __attribute__((ext_vector_type(4)));

__device__ __forceinline__ u16 f2bf(float f) {
    u32 u = __builtin_bit_cast(u32, f);
    u += 0x7FFFu + ((u >> 16) & 1u);
    return (u16)(u >> 16);
}
__device__ __forceinline__ float bf2f(u16 s) {
    return __builtin_bit_cast(float, (u32)s << 16);
}
__device__ __forceinline__ float bflo(u32 w) {
    return __builtin_bit_cast(float, w << 16);
}
__device__ __forceinline__ float bfhi(u32 w) {
    return __builtin_bit_cast(float, w & 0xFFFF0000u);
}
__device__ __forceinline__ u32 pack2bf(float lo, float hi) {
    return (u32)f2bf(lo) | ((u32)f2bf(hi) << 16);
}
__device__ __forceinline__ void gload_lds16(const void* g, void* l) {
    __builtin_amdgcn_global_load_lds(
        (const __attribute__((address_space(1))) unsigned int*)g,
        (__attribute__((address_space(3))) unsigned int*)l, 16, 0, 0);
}
// swizzled byte offset into a [rows][256] bf16 LDS tile (chunk ^= row&7, low 3 bits)
__device__ __forceinline__ int swz(int row, int col) {
    return (row << 9) + ((((col >> 3) ^ (row & 7))) << 4) + ((col & 7) << 1);
}

__constant__ int NODE_OFF[9]  = {0, 119, 124, 136, 148, 158, 164, 170, 172};
__constant__ int NODE_MAXC[9] = {118, 4, 11, 11, 9, 5, 5, 1, 1};

// ---- transpose + bf16-cast the 21 256x256 weight matrices (LDS-tiled) ----
__global__ __launch_bounds__(256) void k_prep_weights(
    const float* __restrict__ W1, const float* __restrict__ W2,
    const float* __restrict__ vW1, const float* __restrict__ vW2,
    const float* __restrict__ hW1, u16* __restrict__ Wt)
{
    __shared__ float lt[64][65];
    int mat = blockIdx.x >> 4;
    int tile = blockIdx.x & 15;
    int tr = (tile >> 2) * 64;   // k-range
    int tc = (tile & 3) * 64;    // n-range
    const float* src;
    if (mat < 5)       src = W1 + (size_t)mat * 65536;
    else if (mat < 10) src = W2 + (size_t)(mat - 5) * 65536;
    else if (mat < 15) src = vW1 + (size_t)(mat - 10) * 65536;
    else if (mat < 20) src = vW2 + (size_t)(mat - 15) * 65536;
    else               src = hW1;
    int tid = threadIdx.x;
#pragma unroll
    for (int r = 0; r < 4; ++r) {
        int k = (tid >> 4) + r * 16;          // 0..63
        int c = (tid & 15) * 4;               // 0..60
        float4 v = *(const float4*)&src[(size_t)(tr + k) * 256 + tc + c];
        lt[k][c + 0] = v.x; lt[k][c + 1] = v.y;
        lt[k][c + 2] = v.z; lt[k][c + 3] = v.w;
    }
    __syncthreads();
#pragma unroll
    for (int r = 0; r < 4; ++r) {
        int n = (tid >> 4) + r * 16;          // 0..63
        int k = (tid & 15) * 4;
        ushort4 o;
        o.x = f2bf(lt[k + 0][n]); o.y = f2bf(lt[k + 1][n]);
        o.z = f2bf(lt[k + 2][n]); o.w = f2bf(lt[k + 3][n]);
        *(ushort4*)&Wt[(size_t)mat * 65536 + (size_t)(tc + n) * 256 + tr + k] = o;
    }
}

// ---- fused setup: vn init + gsum zero | comb table | segment starts ----
__global__ __launch_bounds__(256) void k_misc(
    const float* __restrict__ eemb, const int* __restrict__ batch,
    const float* __restrict__ vn_emb,
    u16* __restrict__ comb, int* __restrict__ starts,
    float* __restrict__ vn, u16* __restrict__ vnbf, float* __restrict__ gsum)
{
    int b = blockIdx.x;
    if (b < 2048) {
        int i = b * 256 + threadIdx.x;
        float v = vn_emb[i & 255];
        vn[i] = v;
        vnbf[i] = f2bf(v);
        gsum[i] = 0.f;
    } else if (b < 2108) {
        int r = b - 2048, c = threadIdx.x;
        int a0 = r / 12, a1 = (r % 12) / 2, a2 = r & 1;
        comb[r * 256 + c] = f2bf(eemb[a0 * 256 + c] + eemb[(5 + a1) * 256 + c] +
                                 eemb[(11 + a2) * 256 + c]);
    } else {
        int g = (b - 2108) * 256 + threadIdx.x;
        if (g > NG) return;
        int lo = 0, hi = NN;
        while (lo < hi) {
            int mid = (lo + hi) >> 1;
            if (batch[mid] < g) lo = mid + 1; else hi = mid;
        }
        starts[g] = lo;
    }
}

// ---- node embedding -> bf16 h; also zero deg ----
__global__ __launch_bounds__(256) void k_embed(const int* __restrict__ x,
                                               const float* __restrict__ node_emb,
                                               u16* __restrict__ hbf,
                                               int* __restrict__ deg)
{
    int i = blockIdx.x * 4 + (threadIdx.x >> 6);
    if (i >= NN) return;
    if ((threadIdx.x & 63) == 0) deg[i] = 0;
    int c = (threadIdx.x & 63) * 4;
    float4 s = make_float4(0.f, 0.f, 0.f, 0.f);
#pragma unroll
    for (int f = 0; f < 9; ++f) {
        int xv = x[i * 9 + f];
        xv = xv < 0 ? 0 : (xv > NODE_MAXC[f] ? NODE_MAXC[f] : xv);
        const float4 t = *(const float4*)&node_emb[(size_t)(NODE_OFF[f] + xv) * 256 + c];
        s.x += t.x; s.y += t.y; s.z += t.z; s.w += t.w;
    }
    ushort4 o;
    o.x = f2bf(s.x); o.y = f2bf(s.y); o.z = f2bf(s.z); o.w = f2bf(s.w);
    *(ushort4*)&hbf[(size_t)i * 256 + c] = o;
}

// ---- CSR-bucket build: slots[d*CAP+p] = src | code<<17 ----
__global__ __launch_bounds__(256) void k_bucket(
    const int* __restrict__ src, const int* __restrict__ dst,
    const int* __restrict__ eattr, int* __restrict__ deg, u32* __restrict__ slots)
{
    int e = blockIdx.x * 256 + threadIdx.x;
    if (e >= NE) return;
    int a0 = eattr[e * 3 + 0]; a0 = a0 < 0 ? 0 : (a0 > 4 ? 4 : a0);
    int a1 = eattr[e * 3 + 1]; a1 = a1 < 0 ? 0 : (a1 > 5 ? 5 : a1);
    int a2 = eattr[e * 3 + 2]; a2 = a2 < 0 ? 0 : (a2 > 1 ? 1 : a2);
    u32 code = (u32)(a0 * 12 + a1 * 2 + a2);
    int d = dst[e];
    int p = atomicAdd(&deg[d], 1);
    if (p < CAP) slots[(size_t)d * CAP + p] = (u32)src[e] | (code << 17);
}

// ---- gather-aggregate: one node per 32-lane HALF-wave (ILP-2 per wave) ----
__global__ __launch_bounds__(256) void k_agg(
    const u16* __restrict__ hbf, const u16* __restrict__ vnbf,
    const int* __restrict__ batch, const u32* __restrict__ slots,
    const int* __restrict__ deg, const u16* __restrict__ comb,
    u16* __restrict__ Abf, const float* __restrict__ epsp)
{
    const int wid = threadIdx.x >> 6, lane = threadIdx.x & 63;
    const int half = lane >> 5, l32 = lane & 31;
    const int d = blockIdx.x * 8 + wid * 2 + half;
    const int c = l32 * 8;
    int nd = deg[d];
    nd = nd > CAP ? CAP : nd;

    const u32* sl = slots + (size_t)d * CAP;
    u32 sv_l = (l32 < nd) ? sl[l32] : 0u;
    int b_l = (l32 < nd) ? batch[sv_l & 0x1FFFFu] : 0;

    float acc[8] = {0.f, 0.f, 0.f, 0.f, 0.f, 0.f, 0.f, 0.f};
    for (int p = 0; p < nd; ++p) {
        int srcl = (lane & 32) | p;
        u32 sv = (u32)__shfl((int)sv_l, srcl);
        int b  = __shfl(b_l, srcl);
        int s  = (int)(sv & 0x1FFFFu);
        int code = (int)(sv >> 17);
        const uint4 hv = *(const uint4*)&hbf[(size_t)s * 256 + c];
        const uint4 vv = *(const uint4*)&vnbf[(size_t)b * 256 + c];
        const uint4 tv = *(const uint4*)&comb[(size_t)code * 256 + c];
        const u32* hw = (const u32*)&hv;
        const u32* vw = (const u32*)&vv;
        const u32* tw = (const u32*)&tv;
#pragma unroll
        for (int e = 0; e < 4; ++e) {
            acc[e * 2 + 0] += fmaxf(bflo(hw[e]) + bflo(vw[e]) + bflo(tw[e]), 0.f);
            acc[e * 2 + 1] += fmaxf(bfhi(hw[e]) + bfhi(vw[e]) + bfhi(tw[e]), 0.f);
        }
    }

    int bd = batch[d];
    float ep = 1.0f + *epsp;
    const uint4 hd = *(const uint4*)&hbf[(size_t)d * 256 + c];
    const uint4 vd = *(const uint4*)&vnbf[(size_t)bd * 256 + c];
    const u32* hw = (const u32*)&hd;
    const u32* vw = (const u32*)&vd;
    uint4 o;
    u32* op = (u32*)&o;
#pragma unroll
    for (int e = 0; e < 4; ++e) {
        float lo = (bflo(hw[e]) + bflo(vw[e])) * ep + acc[e * 2 + 0];
        float hi = (bfhi(hw[e]) + bfhi(vw[e])) * ep + acc[e * 2 + 1];
        op[e] = pack2bf(lo, hi);
    }
    *(uint4*)&Abf[(size_t)d * 256 + c] = o;
}

// ======== shared GEMM building blocks (64-row tile, 8 waves) ========
__device__ __forceinline__ void stageW(const u16* __restrict__ W, u16* Bl,
                                       int k0, int tid, int wid)
{
#pragma unroll
    for (int i = 0; i < 4; ++i) {
        int slot = i * 512 + tid;
        int row = slot >> 3, cch = slot & 7;
        int g = cch ^ (row & 7);
        gload_lds16((const char*)W + (size_t)row * 512 + (size_t)k0 * 2 + (g << 4),
                    (char*)Bl + ((i * 512 + wid * 64) << 4));
    }
}

__device__ __forceinline__ void gemm64(const u16* Tl, u16* Bl, const u16* __restrict__ W,
                                       f32x4 (&acc)[2][4], int wm, int wn,
                                       int lane, int tid, int wid)
{
    const int cl = lane & 15;
    for (int k0 = 0; k0 < 256; k0 += 64) {
        __syncthreads();
        stageW(W, Bl, k0, tid, wid);
        __syncthreads();
#pragma unroll
        for (int kw = 0; kw < 2; ++kw) {
            int q = kw * 4 + (lane >> 4);
            int qt = (k0 >> 3) + q;
            bf16x8 af[2], bfr[4];
#pragma unroll
            for (int t = 0; t < 2; ++t) {
                int ar = wm + t * 16 + cl;
                af[t] = __builtin_bit_cast(bf16x8,
                    *(const uint4*)((const char*)Tl + (ar << 9) + ((qt ^ (ar & 7)) << 4)));
            }
#pragma unroll
            for (int t = 0; t < 4; ++t) {
                int br = wn + t * 16 + cl;
                bfr[t] = __builtin_bit_cast(bf16x8,
                    *(const uint4*)((const char*)Bl + (br << 7) + ((q ^ (br & 7)) << 4)));
            }
#pragma unroll
            for (int i = 0; i < 2; ++i)
#pragma unroll
                for (int j = 0; j < 4; ++j)
                    acc[i][j] = __builtin_amdgcn_mfma_f32_16x16x32_bf16(af[i], bfr[j], acc[i][j], 0, 0, 0);
        }
    }
}

__device__ __forceinline__ void writeT(u16* Tl, const f32x4 (&acc)[2][4],
                                       const float* __restrict__ b1,
                                       int wm, int wn, int lane)
{
    const int cl = lane & 15, rg = lane >> 4;
#pragma unroll
    for (int j = 0; j < 4; ++j) {
        int col = wn + j * 16 + cl;
        float bv = b1[col];
#pragma unroll
        for (int i = 0; i < 2; ++i)
#pragma unroll
            for (int r = 0; r < 4; ++r) {
                int row = wm + i * 16 + rg * 4 + r;
                float v = fmaxf(acc[i][j][r] + bv, 0.f);
                *(u16*)((char*)Tl + swz(row, col)) = f2bf(v);
            }
    }
}

// ======== VARIANT A (control): k_mlpP — W staged per-BK64, 18 barriers ========
__global__ __launch_bounds__(512) void k_mlpP(
    const u16* __restrict__ Abf, u16* __restrict__ hnxt,
    const int* __restrict__ batch,
    const u16* __restrict__ W1t, const u16* __restrict__ W2t,
    const float* __restrict__ b1, const float* __restrict__ b2,
    const float* __restrict__ bng, const float* __restrict__ bnb,
    const float* __restrict__ bnm, const float* __restrict__ bnv,
    float* __restrict__ gsum)
{
    __shared__ __align__(16) u16 Bl[256 * 64];
    __shared__ __align__(16) u16 Tl[64 * 256];
    __shared__ int batchLds[64];
    const int m0 = blockIdx.x * 64;
    const int tid = threadIdx.x, lane = tid & 63, wid = tid >> 6;
    const int wm = (wid >> 2) * 32, wn = (wid & 3) * 64;
    const int cl = lane & 15, rg = lane >> 4;

    if (tid < 64) batchLds[tid] = (m0 + tid < NN) ? batch[m0 + tid] : -1;

#pragma unroll
    for (int i = 0; i < 4; ++i) {
        int slot = i * 512 + tid;
        int row = slot >> 5, cch = slot & 31;
        int g = cch ^ (row & 7);
        gload_lds16((const char*)Abf + (size_t)(m0 + row) * 512 + (g << 4),
                    (char*)Tl + ((i * 512 + wid * 64) << 4));
    }

    f32x4 acc1[2][4] = {};
    gemm64(Tl, Bl, W1t, acc1, wm, wn, lane, tid, wid);
    __syncthreads();
    writeT(Tl, acc1, b1, wm, wn, lane);

    f32x4 acc2[2][4] = {};
    gemm64(Tl, Bl, W2t, acc2, wm, wn, lane, tid, wid);
    __syncthreads();

#pragma unroll
    for (int j = 0; j < 4; ++j) {
        int gn = wn + j * 16 + cl;
        float bv = b2[gn];
        float sc = bng[gn] * rsqrtf(bnv[gn] + 1e-5f);
        float sh = bnb[gn] - bnm[gn] * sc;
        float s = 0.f;
        int gcur = -1;
#pragma unroll
        for (int i = 0; i < 2; ++i) {
#pragma unroll
            for (int r = 0; r < 4; ++r) {
                int row = wm + i * 16 + rg * 4 + r;
                int g = batchLds[row];
                float v = acc2[i][j][r] + bv;
                u16 hb = f2bf(fmaxf(v * sc + sh, 0.f));
                if (g >= 0) hnxt[(size_t)(m0 + row) * 256 + gn] = hb;
                if (g != gcur) {
                    if (gcur >= 0) atomicAdd(&gsum[(size_t)gcur * 256 + gn], s);
                    gcur = g; s = 0.f;
                }
                if (g >= 0) s += bf2f(hb);
            }
        }
        if (gcur >= 0) atomicAdd(&gsum[(size_t)gcur * 256 + gn], s);
    }
}

// ======== VARIANT B: k_mlpR — W FULLY RESIDENT in LDS, 4 barriers total ========
// LDS: Wl 128KB + Tl 32KB = 160KB exactly; 1 block/CU.
__global__ __launch_bounds__(512) void k_mlpR(
    const u16* __restrict__ Abf, u16* __restrict__ hnxt,
    const int* __restrict__ batch,
    const u16* __restrict__ W1t, const u16* __restrict__ W2t,
    const float* __restrict__ b1, const float* __restrict__ b2,
    const float* __restrict__ bng, const float* __restrict__ bnb,
    const float* __restrict__ bnm, const float* __restrict__ bnv,
    float* __restrict__ gsum)
{
    __shared__ __align__(16) u16 Wl[256 * 256];   // 128 KB
    __shared__ __align__(16) u16 Tl[64 * 256];    // 32 KB
    const int m0 = blockIdx.x * 64;
    const int tid = threadIdx.x, lane = tid & 63, wid = tid >> 6;
    const int wm = (wid >> 2) * 32, wn = (wid & 3) * 64;
    const int cl = lane & 15, rg = lane >> 4;

    // stage A (4 rounds) + full W1 (16 rounds)
#pragma unroll
    for (int i = 0; i < 4; ++i) {
        int slot = i * 512 + tid;
        int row = slot >> 5, cch = slot & 31;
        int g = cch ^ (row & 7);
        gload_lds16((const char*)Abf + (size_t)(m0 + row) * 512 + (g << 4),
                    (char*)Tl + ((i * 512 + wid * 64) << 4));
    }
#pragma unroll
    for (int i = 0; i < 16; ++i) {
        int slot = i * 512 + tid;
        int row = slot >> 5, cch = slot & 31;
        int g = cch ^ (row & 7);
        gload_lds16((const char*)W1t + (size_t)row * 512 + (g << 4),
                    (char*)Wl + ((i * 512 + wid * 64) << 4));
    }
    __syncthreads();   // barrier 1: A + W1 ready

    // GEMM1: no internal barriers
    f32x4 acc1[2][4] = {};
#pragma unroll
    for (int p = 0; p < 8; ++p) {
        int ch = p * 4 + rg;
        bf16x8 af[2], bfr[4];
#pragma unroll
        for (int t = 0; t < 2; ++t) {
            int ar = wm + t * 16 + cl;
            af[t] = __builtin_bit_cast(bf16x8,
                *(const uint4*)((const char*)Tl + (ar << 9) + ((ch ^ (ar & 7)) << 4)));
        }
#pragma unroll
        for (int u = 0; u < 4; ++u) {
            int br = wn + u * 16 + cl;
            bfr[u] = __builtin_bit_cast(bf16x8,
                *(const uint4*)((const char*)Wl + (br << 9) + ((ch ^ (br & 7)) << 4)));
        }
#pragma unroll
        for (int t = 0; t < 2; ++t)
#pragma unroll
            for (int u = 0; u < 4; ++u)
                acc1[t][u] = __builtin_amdgcn_mfma_f32_16x16x32_bf16(af[t], bfr[u], acc1[t][u], 0, 0, 0);
    }
    __syncthreads();   // barrier 2: all Tl/Wl reads done

    // T -> Tl; W2 -> Wl
    writeT(Tl, acc1, b1, wm, wn, lane);
#pragma unroll
    for (int i = 0; i < 16; ++i) {
        int slot = i * 512 + tid;
        int row = slot >> 5, cch = slot & 31;
        int g = cch ^ (row & 7);
        gload_lds16((const char*)W2t + (size_t)row * 512 + (g << 4),
                    (char*)Wl + ((i * 512 + wid * 64) << 4));
    }
    __syncthreads();   // barrier 3: T + W2 ready

    // GEMM2: no internal barriers
    f32x4 acc2[2][4] = {};
#pragma unroll
    for (int p = 0; p < 8; ++p) {
        int ch = p * 4 + rg;
        bf16x8 af[2], bfr[4];
#pragma unroll
        for (int t = 0; t < 2; ++t) {
            int ar = wm + t * 16 + cl;
            af[t] = __builtin_bit_cast(bf16x8,
                *(const uint4*)((const char*)Tl + (ar << 9) + ((ch ^ (ar & 7)) << 4)));
        }
#pragma unroll
        for (int u = 0; u < 4; ++u) {
            int br = wn + u * 16 + cl;
            bfr[u] = __builtin_bit_cast(bf16x8,
                *(const uint4*)((const char*)Wl + (br << 9) + ((ch ^ (br & 7)) << 4)));
        }
#pragma unroll
        for (int t = 0; t < 2; ++t)
#pragma unroll
            for (int u = 0; u < 4; ++u)
                acc2[t][u] = __builtin_amdgcn_mfma_f32_16x16x32_bf16(af[t], bfr[u], acc2[t][u], 0, 0, 0);
    }

    // epilogue (batch from global; run-detect pool into gsum)
#pragma unroll
    for (int j = 0; j < 4; ++j) {
        int gn = wn + j * 16 + cl;
        float bv = b2[gn];
        float sc = bng[gn] * rsqrtf(bnv[gn] + 1e-5f);
        float sh = bnb[gn] - bnm[gn] * sc;
        float s = 0.f;
        int gcur = -1;
#pragma unroll
        for (int i = 0; i < 2; ++i) {
#pragma unroll
            for (int r = 0; r < 4; ++r) {
                int row = wm + i * 16 + rg * 4 + r;
                int g = (m0 + row < NN) ? batch[m0 + row] : -1;
                float v = acc2[i][j][r] + bv;
                u16 hb = f2bf(fmaxf(v * sc + sh, 0.f));
                if (g >= 0) hnxt[(size_t)(m0 + row) * 256 + gn] = hb;
                if (g != gcur) {
                    if (gcur >= 0) atomicAdd(&gsum[(size_t)gcur * 256 + gn], s);
                    gcur = g; s = 0.f;
                }
                if (g >= 0) s += bf2f(hb);
            }
        }
        if (gcur >= 0) atomicAdd(&gsum[(size_t)gcur * 256 + gn], s);
    }
}

// ======== fused pool-normalize + vn MLP (32 blocks x 64 graphs) ========
__global__ __launch_bounds__(512) void k_vnmlp(
    float* __restrict__ gsum, const int* __restrict__ starts,
    const u16* __restrict__ W1t, const u16* __restrict__ W2t,
    const float* __restrict__ b1, const float* __restrict__ b2,
    float* __restrict__ vn, u16* __restrict__ vnbf)
{
    __shared__ __align__(16) u16 Bl[256 * 64];
    __shared__ __align__(16) u16 Tl[64 * 256];
    const int m0 = blockIdx.x * 64;
    const int tid = threadIdx.x, lane = tid & 63, wid = tid >> 6;
    const int wm = (wid >> 2) * 32, wn = (wid & 3) * 64;
    const int cl = lane & 15, rg = lane >> 4;

    {
        const int c = lane * 4;
#pragma unroll
        for (int n = 0; n < 8; ++n) {
            int row = wid * 8 + n;
            int g = m0 + row;
            float4 sv = *(const float4*)&gsum[(size_t)g * 256 + c];
            *(float4*)&gsum[(size_t)g * 256 + c] = make_float4(0.f, 0.f, 0.f, 0.f);
            float cnt = (float)(starts[g + 1] - starts[g]);
            float inv = 1.0f / fmaxf(cnt, 1.0f);
            ushort4 o;
            o.x = f2bf(sv.x * inv); o.y = f2bf(sv.y * inv);
            o.z = f2bf(sv.z * inv); o.w = f2bf(sv.w * inv);
            *(ushort4*)((char*)Tl + swz(row, c)) = o;
        }
    }
    __syncthreads();

    f32x4 acc1[2][4] = {};
    gemm64(Tl, Bl, W1t, acc1, wm, wn, lane, tid, wid);
    __syncthreads();
    writeT(Tl, acc1, b1, wm, wn, lane);

    f32x4 acc2[2][4] = {};
    gemm64(Tl, Bl, W2t, acc2, wm, wn, lane, tid, wid);

#pragma unroll
    for (int j = 0; j < 4; ++j) {
        int gn = wn + j * 16 + cl;
        float bv = b2[gn];
#pragma unroll
        for (int i = 0; i < 2; ++i) {
#pragma unroll
            for (int r = 0; r < 4; ++r) {
                int gm = m0 + wm + i * 16 + rg * 4 + r;
                size_t idx = (size_t)gm * 256 + gn;
                float nv = vn[idx] + acc2[i][j][r] + bv;
                vn[idx] = nv;
                vnbf[idx] = f2bf(nv);
            }
        }
    }
}

// ======== fused head: pool-normalize -> relu(.@hW1+hb1) -> matvec hW2 ========
__global__ __launch_bounds__(512) void k_headf(
    const float* __restrict__ gsum, const int* __restrict__ starts,
    const u16* __restrict__ W1t, const float* __restrict__ b1,
    const float* __restrict__ hW2, const float* __restrict__ hb2,
    float* __restrict__ out)
{
    __shared__ __align__(16) u16 Bl[256 * 64];
    __shared__ __align__(16) u16 Tl[64 * 256];
    const int m0 = blockIdx.x * 64;
    const int tid = threadIdx.x, lane = tid & 63, wid = tid >> 6;
    const int wm = (wid >> 2) * 32, wn = (wid & 3) * 64;

    {
        const int c = lane * 4;
#pragma unroll
        for (int n = 0; n < 8; ++n) {
            int row = wid * 8 + n;
            int g = m0 + row;
            float4 sv = *(const float4*)&gsum[(size_t)g * 256 + c];
            float cnt = (float)(starts[g + 1] - starts[g]);
            float inv = 1.0f / fmaxf(cnt, 1.0f);
            ushort4 o;
            o.x = f2bf(sv.x * inv); o.y = f2bf(sv.y * inv);
            o.z = f2bf(sv.z * inv); o.w = f2bf(sv.w * inv);
            *(ushort4*)((char*)Tl + swz(row, c)) = o;
        }
    }
    __syncthreads();

    f32x4 acc1[2][4] = {};
    gemm64(Tl, Bl, W1t, acc1, wm, wn, lane, tid, wid);
    __syncthreads();
    writeT(Tl, acc1, b1, wm, wn, lane);
    __syncthreads();

    int row = tid >> 3, oct = tid & 7;
    float s = 0.f;
#pragma unroll
    for (int c = 0; c < 32; ++c) {
        int col = oct * 32 + c;
        s += bf2f(*(const u16*)((const char*)Tl + swz(row, col))) * hW2[col];
    }
    s += __shfl_down(s, 4);
    s += __shfl_down(s, 2);
    s += __shfl_down(s, 1);
    if (oct == 0) out[m0 + row] = s + hb2[0];
}

extern "C" void kernel_launch(void* const* d_in, const int* in_sizes, int n_in,
                              void* d_out, int out_size, void* d_ws, size_t ws_size,
                              hipStream_t stream)
{
    const int*   x        = (const int*)d_in[0];
    const int*   ei       = (const int*)d_in[1];
    const int*   eattr    = (const int*)d_in[2];
    const int*   batch    = (const int*)d_in[3];
    const float* node_emb = (const float*)d_in[4];
    const float* edge_emb = (const float*)d_in[5];
    const float* vn_emb   = (const float*)d_in[6];
    const float* eps      = (const float*)d_in[7];
    const float* W1       = (const float*)d_in[8];
    const float* b1       = (const float*)d_in[9];
    const float* W2       = (const float*)d_in[10];
    const float* b2       = (const float*)d_in[11];
    const float* bng      = (const float*)d_in[12];
    const float* bnb      = (const float*)d_in[13];
    const float* bnm      = (const float*)d_in[14];
    const float* bnv      = (const float*)d_in[15];
    const float* vW1      = (const float*)d_in[16];
    const float* vb1      = (const float*)d_in[17];
    const float* vW2      = (const float*)d_in[18];
    const float* vb2      = (const float*)d_in[19];
    const float* hW1      = (const float*)d_in[20];
    const float* hb1      = (const float*)d_in[21];
    const float* hW2      = (const float*)d_in[22];
    const float* hb2      = (const float*)d_in[23];
    float* out = (float*)d_out;

    char* ws = (char*)d_ws;
    size_t off = 0;
    auto alloc = [&](size_t b) {
        char* p = ws + off;
        off = (off + b + 255) & ~(size_t)255;
        return p;
    };
    u16*   hbf0 = (u16*)alloc((size_t)NN * 256 * 2);
    u16*   hbf1 = (u16*)alloc((size_t)NN * 256 * 2);
    u16*   Abf  = (u16*)alloc((size_t)NN * 256 * 2 + 65536);  // +64KB tail slack
    float* vn   = (float*)alloc((size_t)NG * 256 * 4);
    u16*   vnbf = (u16*)alloc((size_t)NG * 256 * 2);
    float* gsum = (float*)alloc((size_t)NG * 256 * 4);
    u16*   Wt   = (u16*)alloc((size_t)21 * 65536 * 2);
    int*   starts = (int*)alloc((size_t)(NG + 1) * 4);
    u16*   comb = (u16*)alloc((size_t)60 * 256 * 2);
    int*   deg  = (int*)alloc((size_t)NN * 4);
    u32*   slots = (u32*)alloc((size_t)NN * CAP * 4);

    const int* srcI = ei;
    const int* dstI = ei + NE;

    k_prep_weights<<<21 * 16, 256, 0, stream>>>(W1, W2, vW1, vW2, hW1, Wt);
    k_misc<<<2117, 256, 0, stream>>>(edge_emb, batch, vn_emb, comb, starts, vn, vnbf, gsum);
    k_embed<<<NN / 4, 256, 0, stream>>>(x, node_emb, hbf0, deg);
    k_bucket<<<(NE + 255) / 256, 256, 0, stream>>>(srcI, dstI, eattr, deg, slots);

    const int GBIG = (NN + 63) / 64;   // 938 blocks
    const int GSM  = NG / 64;          // 32 blocks

    u16* hcur = hbf0;
    u16* hnxt = hbf1;
    for (int l = 0; l < NL; ++l) {
        k_agg<<<NN / 8, 256, 0, stream>>>(hcur, vnbf, batch, slots, deg, comb, Abf, eps + l);
        const u16* w1p = Wt + (size_t)(0 + l) * 65536;
        const u16* w2p = Wt + (size_t)(5 + l) * 65536;
        if (l == 1 || l == 3) {
            k_mlpR<<<GBIG, 512, 0, stream>>>(Abf, hnxt, batch, w1p, w2p,
                                             b1 + l * 256, b2 + l * 256,
                                             bng + l * 256, bnb + l * 256,
                                             bnm + l * 256, bnv + l * 256, gsum);
        } else {
            k_mlpP<<<GBIG, 512, 0, stream>>>(Abf, hnxt, batch, w1p, w2p,
                                             b1 + l * 256, b2 + l * 256,
                                             bng + l * 256, bnb + l * 256,
                                             bnm + l * 256, bnv + l * 256, gsum);
        }
        if (l < NL - 1) {
            k_vnmlp<<<GSM, 512, 0, stream>>>(gsum, starts,
                                             Wt + (size_t)(10 + l) * 65536,
                                             Wt + (size_t)(15 + l) * 65536,
                                             vb1 + l * 256, vb2 + l * 256,
                                             vn, vnbf);
        }
        u16* t = hcur; hcur = hnxt; hnxt = t;
    }
    k_headf<<<GSM, 512, 0, stream>>>(gsum, starts, Wt + (size_t)20 * 65536,
                                     hb1, hW2, hb2, out);
}

// Round 15
// 545.927 us; speedup vs baseline: 1.2108x; 1.1025x over previous
//
#include <hip/hip_runtime.h>

#define NN 60000
#define NE 180000
#define NG 2048
#define NL 5
#define CAP 32

typedef unsigned short u16;
typedef unsigned int u32;
typedef __bf16 bf16x8 __attribute__((ext_vector_type(8)));
typedef float f32x4 __attribute__((ext_vector_type(4)));

__device__ __forceinline__ u16 f2bf(float f) {
    u32 u = __builtin_bit_cast(u32, f);
    u += 0x7FFFu + ((u >> 16) & 1u);
    return (u16)(u >> 16);
}
__device__ __forceinline__ float bf2f(u16 s) {
    return __builtin_bit_cast(float, (u32)s << 16);
}
__device__ __forceinline__ float bflo(u32 w) {
    return __builtin_bit_cast(float, w << 16);
}
__device__ __forceinline__ float bfhi(u32 w) {
    return __builtin_bit_cast(float, w & 0xFFFF0000u);
}
__device__ __forceinline__ u32 pack2bf(float lo, float hi) {
    return (u32)f2bf(lo) | ((u32)f2bf(hi) << 16);
}
__device__ __forceinline__ void gload_lds16(const void* g, void* l) {
    __builtin_amdgcn_global_load_lds(
        (const __attribute__((address_space(1))) unsigned int*)g,
        (__attribute__((address_space(3))) unsigned int*)l, 16, 0, 0);
}
// swizzled byte offset into a [rows][256] bf16 LDS tile (chunk ^= row&7, low 3 bits)
__device__ __forceinline__ int swz(int row, int col) {
    return (row << 9) + ((((col >> 3) ^ (row & 7))) << 4) + ((col & 7) << 1);
}

__constant__ int NODE_OFF[9]  = {0, 119, 124, 136, 148, 158, 164, 170, 172};
__constant__ int NODE_MAXC[9] = {118, 4, 11, 11, 9, 5, 5, 1, 1};

// ---- transpose + bf16-cast the 21 256x256 weight matrices (LDS-tiled) ----
__global__ __launch_bounds__(256) void k_prep_weights(
    const float* __restrict__ W1, const float* __restrict__ W2,
    const float* __restrict__ vW1, const float* __restrict__ vW2,
    const float* __restrict__ hW1, u16* __restrict__ Wt)
{
    __shared__ float lt[64][65];
    int mat = blockIdx.x >> 4;
    int tile = blockIdx.x & 15;
    int tr = (tile >> 2) * 64;
    int tc = (tile & 3) * 64;
    const float* src;
    if (mat < 5)       src = W1 + (size_t)mat * 65536;
    else if (mat < 10) src = W2 + (size_t)(mat - 5) * 65536;
    else if (mat < 15) src = vW1 + (size_t)(mat - 10) * 65536;
    else if (mat < 20) src = vW2 + (size_t)(mat - 15) * 65536;
    else               src = hW1;
    int tid = threadIdx.x;
#pragma unroll
    for (int r = 0; r < 4; ++r) {
        int k = (tid >> 4) + r * 16;
        int c = (tid & 15) * 4;
        float4 v = *(const float4*)&src[(size_t)(tr + k) * 256 + tc + c];
        lt[k][c + 0] = v.x; lt[k][c + 1] = v.y;
        lt[k][c + 2] = v.z; lt[k][c + 3] = v.w;
    }
    __syncthreads();
#pragma unroll
    for (int r = 0; r < 4; ++r) {
        int n = (tid >> 4) + r * 16;
        int k = (tid & 15) * 4;
        ushort4 o;
        o.x = f2bf(lt[k + 0][n]); o.y = f2bf(lt[k + 1][n]);
        o.z = f2bf(lt[k + 2][n]); o.w = f2bf(lt[k + 3][n]);
        *(ushort4*)&Wt[(size_t)mat * 65536 + (size_t)(tc + n) * 256 + tr + k] = o;
    }
}

// ---- fused setup: vn init + gsum zero | comb table | segment starts ----
__global__ __launch_bounds__(256) void k_misc(
    const float* __restrict__ eemb, const int* __restrict__ batch,
    const float* __restrict__ vn_emb,
    u16* __restrict__ comb, int* __restrict__ starts,
    float* __restrict__ vn, u16* __restrict__ vnbf, float* __restrict__ gsum)
{
    int b = blockIdx.x;
    if (b < 2048) {
        int i = b * 256 + threadIdx.x;
        float v = vn_emb[i & 255];
        vn[i] = v;
        vnbf[i] = f2bf(v);
        gsum[i] = 0.f;
    } else if (b < 2108) {
        int r = b - 2048, c = threadIdx.x;
        int a0 = r / 12, a1 = (r % 12) / 2, a2 = r & 1;
        comb[r * 256 + c] = f2bf(eemb[a0 * 256 + c] + eemb[(5 + a1) * 256 + c] +
                                 eemb[(11 + a2) * 256 + c]);
    } else {
        int g = (b - 2108) * 256 + threadIdx.x;
        if (g > NG) return;
        int lo = 0, hi = NN;
        while (lo < hi) {
            int mid = (lo + hi) >> 1;
            if (batch[mid] < g) lo = mid + 1; else hi = mid;
        }
        starts[g] = lo;
    }
}

// ---- node embedding -> bf16 h; also zero deg ----
__global__ __launch_bounds__(256) void k_embed(const int* __restrict__ x,
                                               const float* __restrict__ node_emb,
                                               u16* __restrict__ hbf,
                                               int* __restrict__ deg)
{
    int i = blockIdx.x * 4 + (threadIdx.x >> 6);
    if (i >= NN) return;
    if ((threadIdx.x & 63) == 0) deg[i] = 0;
    int c = (threadIdx.x & 63) * 4;
    float4 s = make_float4(0.f, 0.f, 0.f, 0.f);
#pragma unroll
    for (int f = 0; f < 9; ++f) {
        int xv = x[i * 9 + f];
        xv = xv < 0 ? 0 : (xv > NODE_MAXC[f] ? NODE_MAXC[f] : xv);
        const float4 t = *(const float4*)&node_emb[(size_t)(NODE_OFF[f] + xv) * 256 + c];
        s.x += t.x; s.y += t.y; s.z += t.z; s.w += t.w;
    }
    ushort4 o;
    o.x = f2bf(s.x); o.y = f2bf(s.y); o.z = f2bf(s.z); o.w = f2bf(s.w);
    *(ushort4*)&hbf[(size_t)i * 256 + c] = o;
}

// ---- CSR-bucket build: slots[d*CAP+p] = src | code<<17 ----
__global__ __launch_bounds__(256) void k_bucket(
    const int* __restrict__ src, const int* __restrict__ dst,
    const int* __restrict__ eattr, int* __restrict__ deg, u32* __restrict__ slots)
{
    int e = blockIdx.x * 256 + threadIdx.x;
    if (e >= NE) return;
    int a0 = eattr[e * 3 + 0]; a0 = a0 < 0 ? 0 : (a0 > 4 ? 4 : a0);
    int a1 = eattr[e * 3 + 1]; a1 = a1 < 0 ? 0 : (a1 > 5 ? 5 : a1);
    int a2 = eattr[e * 3 + 2]; a2 = a2 < 0 ? 0 : (a2 > 1 ? 1 : a2);
    u32 code = (u32)(a0 * 12 + a1 * 2 + a2);
    int d = dst[e];
    int p = atomicAdd(&deg[d], 1);
    if (p < CAP) slots[(size_t)d * CAP + p] = (u32)src[e] | (code << 17);
}

// ---- gather-aggregate: one node per 32-lane HALF-wave (ILP-2 per wave) ----
__global__ __launch_bounds__(256) void k_agg(
    const u16* __restrict__ hbf, const u16* __restrict__ vnbf,
    const int* __restrict__ batch, const u32* __restrict__ slots,
    const int* __restrict__ deg, const u16* __restrict__ comb,
    u16* __restrict__ Abf, const float* __restrict__ epsp)
{
    const int wid = threadIdx.x >> 6, lane = threadIdx.x & 63;
    const int half = lane >> 5, l32 = lane & 31;
    const int d = blockIdx.x * 8 + wid * 2 + half;
    const int c = l32 * 8;
    int nd = deg[d];
    nd = nd > CAP ? CAP : nd;

    const u32* sl = slots + (size_t)d * CAP;
    u32 sv_l = (l32 < nd) ? sl[l32] : 0u;
    int b_l = (l32 < nd) ? batch[sv_l & 0x1FFFFu] : 0;

    float acc[8] = {0.f, 0.f, 0.f, 0.f, 0.f, 0.f, 0.f, 0.f};
    for (int p = 0; p < nd; ++p) {
        int srcl = (lane & 32) | p;
        u32 sv = (u32)__shfl((int)sv_l, srcl);
        int b  = __shfl(b_l, srcl);
        int s  = (int)(sv & 0x1FFFFu);
        int code = (int)(sv >> 17);
        const uint4 hv = *(const uint4*)&hbf[(size_t)s * 256 + c];
        const uint4 vv = *(const uint4*)&vnbf[(size_t)b * 256 + c];
        const uint4 tv = *(const uint4*)&comb[(size_t)code * 256 + c];
        const u32* hw = (const u32*)&hv;
        const u32* vw = (const u32*)&vv;
        const u32* tw = (const u32*)&tv;
#pragma unroll
        for (int e = 0; e < 4; ++e) {
            acc[e * 2 + 0] += fmaxf(bflo(hw[e]) + bflo(vw[e]) + bflo(tw[e]), 0.f);
            acc[e * 2 + 1] += fmaxf(bfhi(hw[e]) + bfhi(vw[e]) + bfhi(tw[e]), 0.f);
        }
    }

    int bd = batch[d];
    float ep = 1.0f + *epsp;
    const uint4 hd = *(const uint4*)&hbf[(size_t)d * 256 + c];
    const uint4 vd = *(const uint4*)&vnbf[(size_t)bd * 256 + c];
    const u32* hw = (const u32*)&hd;
    const u32* vw = (const u32*)&vd;
    uint4 o;
    u32* op = (u32*)&o;
#pragma unroll
    for (int e = 0; e < 4; ++e) {
        float lo = (bflo(hw[e]) + bflo(vw[e])) * ep + acc[e * 2 + 0];
        float hi = (bfhi(hw[e]) + bfhi(vw[e])) * ep + acc[e * 2 + 1];
        op[e] = pack2bf(lo, hi);
    }
    *(uint4*)&Abf[(size_t)d * 256 + c] = o;
}

// ======== shared GEMM building blocks ========
__device__ __forceinline__ void stageW(const u16* __restrict__ W, u16* Bl,
                                       int k0, int tid, int wid)
{
#pragma unroll
    for (int i = 0; i < 4; ++i) {
        int slot = i * 512 + tid;
        int row = slot >> 3, cch = slot & 7;
        int g = cch ^ (row & 7);
        gload_lds16((const char*)W + (size_t)row * 512 + (size_t)k0 * 2 + (g << 4),
                    (char*)Bl + ((i * 512 + wid * 64) << 4));
    }
}

__device__ __forceinline__ void gemm64(const u16* Tl, u16* Bl, const u16* __restrict__ W,
                                       f32x4 (&acc)[2][4], int wm, int wn,
                                       int lane, int tid, int wid)
{
    const int cl = lane & 15;
    for (int k0 = 0; k0 < 256; k0 += 64) {
        __syncthreads();
        stageW(W, Bl, k0, tid, wid);
        __syncthreads();
#pragma unroll
        for (int kw = 0; kw < 2; ++kw) {
            int q = kw * 4 + (lane >> 4);
            int qt = (k0 >> 3) + q;
            bf16x8 af[2], bfr[4];
#pragma unroll
            for (int t = 0; t < 2; ++t) {
                int ar = wm + t * 16 + cl;
                af[t] = __builtin_bit_cast(bf16x8,
                    *(const uint4*)((const char*)Tl + (ar << 9) + ((qt ^ (ar & 7)) << 4)));
            }
#pragma unroll
            for (int t = 0; t < 4; ++t) {
                int br = wn + t * 16 + cl;
                bfr[t] = __builtin_bit_cast(bf16x8,
                    *(const uint4*)((const char*)Bl + (br << 7) + ((q ^ (br & 7)) << 4)));
            }
#pragma unroll
            for (int i = 0; i < 2; ++i)
#pragma unroll
                for (int j = 0; j < 4; ++j)
                    acc[i][j] = __builtin_amdgcn_mfma_f32_16x16x32_bf16(af[i], bfr[j], acc[i][j], 0, 0, 0);
        }
    }
}

__device__ __forceinline__ void writeT(u16* Tl, const f32x4 (&acc)[2][4],
                                       const float* __restrict__ b1,
                                       int wm, int wn, int lane)
{
    const int cl = lane & 15, rg = lane >> 4;
#pragma unroll
    for (int j = 0; j < 4; ++j) {
        int col = wn + j * 16 + cl;
        float bv = b1[col];
#pragma unroll
        for (int i = 0; i < 2; ++i)
#pragma unroll
            for (int r = 0; r < 4; ++r) {
                int row = wm + i * 16 + rg * 4 + r;
                float v = fmaxf(acc[i][j][r] + bv, 0.f);
                *(u16*)((char*)Tl + swz(row, col)) = f2bf(v);
            }
    }
}

// ======== VARIANT A (control): k_mlpP — BM=64, 2 blocks/CU ========
__global__ __launch_bounds__(512) void k_mlpP(
    const u16* __restrict__ Abf, u16* __restrict__ hnxt,
    const int* __restrict__ batch,
    const u16* __restrict__ W1t, const u16* __restrict__ W2t,
    const float* __restrict__ b1, const float* __restrict__ b2,
    const float* __restrict__ bng, const float* __restrict__ bnb,
    const float* __restrict__ bnm, const float* __restrict__ bnv,
    float* __restrict__ gsum)
{
    __shared__ __align__(16) u16 Bl[256 * 64];
    __shared__ __align__(16) u16 Tl[64 * 256];
    __shared__ int batchLds[64];
    const int m0 = blockIdx.x * 64;
    const int tid = threadIdx.x, lane = tid & 63, wid = tid >> 6;
    const int wm = (wid >> 2) * 32, wn = (wid & 3) * 64;
    const int cl = lane & 15, rg = lane >> 4;

    if (tid < 64) batchLds[tid] = (m0 + tid < NN) ? batch[m0 + tid] : -1;

#pragma unroll
    for (int i = 0; i < 4; ++i) {
        int slot = i * 512 + tid;
        int row = slot >> 5, cch = slot & 31;
        int g = cch ^ (row & 7);
        gload_lds16((const char*)Abf + (size_t)(m0 + row) * 512 + (g << 4),
                    (char*)Tl + ((i * 512 + wid * 64) << 4));
    }

    f32x4 acc1[2][4] = {};
    gemm64(Tl, Bl, W1t, acc1, wm, wn, lane, tid, wid);
    __syncthreads();
    writeT(Tl, acc1, b1, wm, wn, lane);

    f32x4 acc2[2][4] = {};
    gemm64(Tl, Bl, W2t, acc2, wm, wn, lane, tid, wid);
    __syncthreads();

#pragma unroll
    for (int j = 0; j < 4; ++j) {
        int gn = wn + j * 16 + cl;
        float bv = b2[gn];
        float sc = bng[gn] * rsqrtf(bnv[gn] + 1e-5f);
        float sh = bnb[gn] - bnm[gn] * sc;
        float s = 0.f;
        int gcur = -1;
#pragma unroll
        for (int i = 0; i < 2; ++i) {
#pragma unroll
            for (int r = 0; r < 4; ++r) {
                int row = wm + i * 16 + rg * 4 + r;
                int g = batchLds[row];
                float v = acc2[i][j][r] + bv;
                u16 hb = f2bf(fmaxf(v * sc + sh, 0.f));
                if (g >= 0) hnxt[(size_t)(m0 + row) * 256 + gn] = hb;
                if (g != gcur) {
                    if (gcur >= 0) atomicAdd(&gsum[(size_t)gcur * 256 + gn], s);
                    gcur = g; s = 0.f;
                }
                if (g >= 0) s += bf2f(hb);
            }
        }
        if (gcur >= 0) atomicAdd(&gsum[(size_t)gcur * 256 + gn], s);
    }
}

// ======== VARIANT B: k_mlpS — BM=32, same phase structure, 3 blocks/CU ========
__global__ __launch_bounds__(512) void k_mlpS(
    const u16* __restrict__ Abf, u16* __restrict__ hnxt,
    const int* __restrict__ batch,
    const u16* __restrict__ W1t, const u16* __restrict__ W2t,
    const float* __restrict__ b1, const float* __restrict__ b2,
    const float* __restrict__ bng, const float* __restrict__ bnb,
    const float* __restrict__ bnm, const float* __restrict__ bnv,
    float* __restrict__ gsum)
{
    __shared__ __align__(16) u16 Bl[256 * 64];   // 32 KB W panel
    __shared__ __align__(16) u16 Tl[32 * 256];   // 16 KB A/T tile
    __shared__ int batchLds[32];
    const int m0 = blockIdx.x * 32;
    const int tid = threadIdx.x, lane = tid & 63, wid = tid >> 6;
    const int wn = wid * 32;                     // each wave owns 32 cols, all 32 rows
    const int cl = lane & 15, rg = lane >> 4;

    if (tid < 32) batchLds[tid] = batch[m0 + tid];   // NN % 32 == 0

    // stage A[32][256]: 1024 slots, 2 rounds
#pragma unroll
    for (int i = 0; i < 2; ++i) {
        int slot = i * 512 + tid;
        int row = slot >> 5, cch = slot & 31;
        int g = cch ^ (row & 7);
        gload_lds16((const char*)Abf + (size_t)(m0 + row) * 512 + (g << 4),
                    (char*)Tl + ((i * 512 + wid * 64) << 4));
    }

    // ---- GEMM1: acc1 = A @ W1 (same stage-drain phases as mlpP) ----
    f32x4 acc1[2][2] = {};
    for (int k0 = 0; k0 < 256; k0 += 64) {
        __syncthreads();
        stageW(W1t, Bl, k0, tid, wid);
        __syncthreads();
#pragma unroll
        for (int kw = 0; kw < 2; ++kw) {
            int q = kw * 4 + rg;
            int qt = (k0 >> 3) + q;
            bf16x8 af[2], bfr[2];
#pragma unroll
            for (int t = 0; t < 2; ++t) {
                int ar = t * 16 + cl;
                af[t] = __builtin_bit_cast(bf16x8,
                    *(const uint4*)((const char*)Tl + (ar << 9) + ((qt ^ (ar & 7)) << 4)));
            }
#pragma unroll
            for (int u = 0; u < 2; ++u) {
                int br = wn + u * 16 + cl;
                bfr[u] = __builtin_bit_cast(bf16x8,
                    *(const uint4*)((const char*)Bl + (br << 7) + ((q ^ (br & 7)) << 4)));
            }
#pragma unroll
            for (int t = 0; t < 2; ++t)
#pragma unroll
                for (int u = 0; u < 2; ++u)
                    acc1[t][u] = __builtin_amdgcn_mfma_f32_16x16x32_bf16(af[t], bfr[u], acc1[t][u], 0, 0, 0);
        }
    }
    __syncthreads();

    // ---- T = relu(acc1 + b1) -> Tl ----
#pragma unroll
    for (int j = 0; j < 2; ++j) {
        int col = wn + j * 16 + cl;
        float bv = b1[col];
#pragma unroll
        for (int i = 0; i < 2; ++i)
#pragma unroll
            for (int r = 0; r < 4; ++r) {
                int row = i * 16 + rg * 4 + r;
                float v = fmaxf(acc1[i][j][r] + bv, 0.f);
                *(u16*)((char*)Tl + swz(row, col)) = f2bf(v);
            }
    }

    // ---- GEMM2: acc2 = T @ W2 ----
    f32x4 acc2[2][2] = {};
    for (int k0 = 0; k0 < 256; k0 += 64) {
        __syncthreads();
        stageW(W2t, Bl, k0, tid, wid);
        __syncthreads();
#pragma unroll
        for (int kw = 0; kw < 2; ++kw) {
            int q = kw * 4 + rg;
            int qt = (k0 >> 3) + q;
            bf16x8 af[2], bfr[2];
#pragma unroll
            for (int t = 0; t < 2; ++t) {
                int ar = t * 16 + cl;
                af[t] = __builtin_bit_cast(bf16x8,
                    *(const uint4*)((const char*)Tl + (ar << 9) + ((qt ^ (ar & 7)) << 4)));
            }
#pragma unroll
            for (int u = 0; u < 2; ++u) {
                int br = wn + u * 16 + cl;
                bfr[u] = __builtin_bit_cast(bf16x8,
                    *(const uint4*)((const char*)Bl + (br << 7) + ((q ^ (br & 7)) << 4)));
            }
#pragma unroll
            for (int t = 0; t < 2; ++t)
#pragma unroll
                for (int u = 0; u < 2; ++u)
                    acc2[t][u] = __builtin_amdgcn_mfma_f32_16x16x32_bf16(af[t], bfr[u], acc2[t][u], 0, 0, 0);
        }
    }

    // ---- epilogue ----
#pragma unroll
    for (int j = 0; j < 2; ++j) {
        int gn = wn + j * 16 + cl;
        float bv = b2[gn];
        float sc = bng[gn] * rsqrtf(bnv[gn] + 1e-5f);
        float sh = bnb[gn] - bnm[gn] * sc;
        float s = 0.f;
        int gcur = -1;
#pragma unroll
        for (int i = 0; i < 2; ++i) {
#pragma unroll
            for (int r = 0; r < 4; ++r) {
                int row = i * 16 + rg * 4 + r;
                int g = batchLds[row];
                float v = acc2[i][j][r] + bv;
                u16 hb = f2bf(fmaxf(v * sc + sh, 0.f));
                hnxt[(size_t)(m0 + row) * 256 + gn] = hb;
                if (g != gcur) {
                    if (gcur >= 0) atomicAdd(&gsum[(size_t)gcur * 256 + gn], s);
                    gcur = g; s = 0.f;
                }
                s += bf2f(hb);
            }
        }
        if (gcur >= 0) atomicAdd(&gsum[(size_t)gcur * 256 + gn], s);
    }
}

// ======== fused pool-normalize + vn MLP (32 blocks x 64 graphs) ========
__global__ __launch_bounds__(512) void k_vnmlp(
    float* __restrict__ gsum, const int* __restrict__ starts,
    const u16* __restrict__ W1t, const u16* __restrict__ W2t,
    const float* __restrict__ b1, const float* __restrict__ b2,
    float* __restrict__ vn, u16* __restrict__ vnbf)
{
    __shared__ __align__(16) u16 Bl[256 * 64];
    __shared__ __align__(16) u16 Tl[64 * 256];
    const int m0 = blockIdx.x * 64;
    const int tid = threadIdx.x, lane = tid & 63, wid = tid >> 6;
    const int wm = (wid >> 2) * 32, wn = (wid & 3) * 64;
    const int cl = lane & 15, rg = lane >> 4;

    {
        const int c = lane * 4;
#pragma unroll
        for (int n = 0; n < 8; ++n) {
            int row = wid * 8 + n;
            int g = m0 + row;
            float4 sv = *(const float4*)&gsum[(size_t)g * 256 + c];
            *(float4*)&gsum[(size_t)g * 256 + c] = make_float4(0.f, 0.f, 0.f, 0.f);
            float cnt = (float)(starts[g + 1] - starts[g]);
            float inv = 1.0f / fmaxf(cnt, 1.0f);
            ushort4 o;
            o.x = f2bf(sv.x * inv); o.y = f2bf(sv.y * inv);
            o.z = f2bf(sv.z * inv); o.w = f2bf(sv.w * inv);
            *(ushort4*)((char*)Tl + swz(row, c)) = o;
        }
    }
    __syncthreads();

    f32x4 acc1[2][4] = {};
    gemm64(Tl, Bl, W1t, acc1, wm, wn, lane, tid, wid);
    __syncthreads();
    writeT(Tl, acc1, b1, wm, wn, lane);

    f32x4 acc2[2][4] = {};
    gemm64(Tl, Bl, W2t, acc2, wm, wn, lane, tid, wid);

#pragma unroll
    for (int j = 0; j < 4; ++j) {
        int gn = wn + j * 16 + cl;
        float bv = b2[gn];
#pragma unroll
        for (int i = 0; i < 2; ++i) {
#pragma unroll
            for (int r = 0; r < 4; ++r) {
                int gm = m0 + wm + i * 16 + rg * 4 + r;
                size_t idx = (size_t)gm * 256 + gn;
                float nv = vn[idx] + acc2[i][j][r] + bv;
                vn[idx] = nv;
                vnbf[idx] = f2bf(nv);
            }
        }
    }
}

// ======== fused head: pool-normalize -> relu(.@hW1+hb1) -> matvec hW2 ========
__global__ __launch_bounds__(512) void k_headf(
    const float* __restrict__ gsum, const int* __restrict__ starts,
    const u16* __restrict__ W1t, const float* __restrict__ b1,
    const float* __restrict__ hW2, const float* __restrict__ hb2,
    float* __restrict__ out)
{
    __shared__ __align__(16) u16 Bl[256 * 64];
    __shared__ __align__(16) u16 Tl[64 * 256];
    const int m0 = blockIdx.x * 64;
    const int tid = threadIdx.x, lane = tid & 63, wid = tid >> 6;
    const int wm = (wid >> 2) * 32, wn = (wid & 3) * 64;

    {
        const int c = lane * 4;
#pragma unroll
        for (int n = 0; n < 8; ++n) {
            int row = wid * 8 + n;
            int g = m0 + row;
            float4 sv = *(const float4*)&gsum[(size_t)g * 256 + c];
            float cnt = (float)(starts[g + 1] - starts[g]);
            float inv = 1.0f / fmaxf(cnt, 1.0f);
            ushort4 o;
            o.x = f2bf(sv.x * inv); o.y = f2bf(sv.y * inv);
            o.z = f2bf(sv.z * inv); o.w = f2bf(sv.w * inv);
            *(ushort4*)((char*)Tl + swz(row, c)) = o;
        }
    }
    __syncthreads();

    f32x4 acc1[2][4] = {};
    gemm64(Tl, Bl, W1t, acc1, wm, wn, lane, tid, wid);
    __syncthreads();
    writeT(Tl, acc1, b1, wm, wn, lane);
    __syncthreads();

    int row = tid >> 3, oct = tid & 7;
    float s = 0.f;
#pragma unroll
    for (int c = 0; c < 32; ++c) {
        int col = oct * 32 + c;
        s += bf2f(*(const u16*)((const char*)Tl + swz(row, col))) * hW2[col];
    }
    s += __shfl_down(s, 4);
    s += __shfl_down(s, 2);
    s += __shfl_down(s, 1);
    if (oct == 0) out[m0 + row] = s + hb2[0];
}

extern "C" void kernel_launch(void* const* d_in, const int* in_sizes, int n_in,
                              void* d_out, int out_size, void* d_ws, size_t ws_size,
                              hipStream_t stream)
{
    const int*   x        = (const int*)d_in[0];
    const int*   ei       = (const int*)d_in[1];
    const int*   eattr    = (const int*)d_in[2];
    const int*   batch    = (const int*)d_in[3];
    const float* node_emb = (const float*)d_in[4];
    const float* edge_emb = (const float*)d_in[5];
    const float* vn_emb   = (const float*)d_in[6];
    const float* eps      = (const float*)d_in[7];
    const float* W1       = (const float*)d_in[8];
    const float* b1       = (const float*)d_in[9];
    const float* W2       = (const float*)d_in[10];
    const float* b2       = (const float*)d_in[11];
    const float* bng      = (const float*)d_in[12];
    const float* bnb      = (const float*)d_in[13];
    const float* bnm      = (const float*)d_in[14];
    const float* bnv      = (const float*)d_in[15];
    const float* vW1      = (const float*)d_in[16];
    const float* vb1      = (const float*)d_in[17];
    const float* vW2      = (const float*)d_in[18];
    const float* vb2      = (const float*)d_in[19];
    const float* hW1      = (const float*)d_in[20];
    const float* hb1      = (const float*)d_in[21];
    const float* hW2      = (const float*)d_in[22];
    const float* hb2      = (const float*)d_in[23];
    float* out = (float*)d_out;

    char* ws = (char*)d_ws;
    size_t off = 0;
    auto alloc = [&](size_t b) {
        char* p = ws + off;
        off = (off + b + 255) & ~(size_t)255;
        return p;
    };
    u16*   hbf0 = (u16*)alloc((size_t)NN * 256 * 2);
    u16*   hbf1 = (u16*)alloc((size_t)NN * 256 * 2);
    u16*   Abf  = (u16*)alloc((size_t)NN * 256 * 2 + 65536);
    float* vn   = (float*)alloc((size_t)NG * 256 * 4);
    u16*   vnbf = (u16*)alloc((size_t)NG * 256 * 2);
    float* gsum = (float*)alloc((size_t)NG * 256 * 4);
    u16*   Wt   = (u16*)alloc((size_t)21 * 65536 * 2);
    int*   starts = (int*)alloc((size_t)(NG + 1) * 4);
    u16*   comb = (u16*)alloc((size_t)60 * 256 * 2);
    int*   deg  = (int*)alloc((size_t)NN * 4);
    u32*   slots = (u32*)alloc((size_t)NN * CAP * 4);

    const int* srcI = ei;
    const int* dstI = ei + NE;

    k_prep_weights<<<21 * 16, 256, 0, stream>>>(W1, W2, vW1, vW2, hW1, Wt);
    k_misc<<<2117, 256, 0, stream>>>(edge_emb, batch, vn_emb, comb, starts, vn, vnbf, gsum);
    k_embed<<<NN / 4, 256, 0, stream>>>(x, node_emb, hbf0, deg);
    k_bucket<<<(NE + 255) / 256, 256, 0, stream>>>(srcI, dstI, eattr, deg, slots);

    const int GBIG = (NN + 63) / 64;   // 938 blocks (mlpP)
    const int GS32 = NN / 32;          // 1875 blocks (mlpS)
    const int GSM  = NG / 64;          // 32 blocks

    u16* hcur = hbf0;
    u16* hnxt = hbf1;
    for (int l = 0; l < NL; ++l) {
        k_agg<<<NN / 8, 256, 0, stream>>>(hcur, vnbf, batch, slots, deg, comb, Abf, eps + l);
        const u16* w1p = Wt + (size_t)(0 + l) * 65536;
        const u16* w2p = Wt + (size_t)(5 + l) * 65536;
        if (l == 0 || l == 2 || l == 4) {
            k_mlpS<<<GS32, 512, 0, stream>>>(Abf, hnxt, batch, w1p, w2p,
                                             b1 + l * 256, b2 + l * 256,
                                             bng + l * 256, bnb + l * 256,
                                             bnm + l * 256, bnv + l * 256, gsum);
        } else {
            k_mlpP<<<GBIG, 512, 0, stream>>>(Abf, hnxt, batch, w1p, w2p,
                                             b1 + l * 256, b2 + l * 256,
                                             bng + l * 256, bnb + l * 256,
                                             bnm + l * 256, bnv + l * 256, gsum);
        }
        if (l < NL - 1) {
            k_vnmlp<<<GSM, 512, 0, stream>>>(gsum, starts,
                                             Wt + (size_t)(10 + l) * 65536,
                                             Wt + (size_t)(15 + l) * 65536,
                                             vb1 + l * 256, vb2 + l * 256,
                                             vn, vnbf);
        }
        u16* t = hcur; hcur = hnxt; hnxt = t;
    }
    k_headf<<<GSM, 512, 0, stream>>>(gsum, starts, Wt + (size_t)20 * 65536,
                                     hb1, hW2, hb2, out);
}

// Round 17
// 542.053 us; speedup vs baseline: 1.2195x; 1.0071x over previous
//
#include <hip/hip_runtime.h>

#define NN 60000
#define NE 180000
#define NG 2048
#define NL 5
#define CAP 32

typedef unsigned short u16;
typedef unsigned int u32;
typedef __bf16 bf16x8 __attribute__((ext_vector_type(8)));
typedef float f32x4 __attribute__((ext_vector_type(4)));

__device__ __forceinline__ u16 f2bf(float f) {
    u32 u = __builtin_bit_cast(u32, f);
    u += 0x7FFFu + ((u >> 16) & 1u);
    return (u16)(u >> 16);
}
__device__ __forceinline__ float bf2f(u16 s) {
    return __builtin_bit_cast(float, (u32)s << 16);
}
__device__ __forceinline__ float bflo(u32 w) {
    return __builtin_bit_cast(float, w << 16);
}
__device__ __forceinline__ float bfhi(u32 w) {
    return __builtin_bit_cast(float, w & 0xFFFF0000u);
}
__device__ __forceinline__ u32 pack2bf(float lo, float hi) {
    return (u32)f2bf(lo) | ((u32)f2bf(hi) << 16);
}
__device__ __forceinline__ void gload_lds16(const void* g, void* l) {
    __builtin_amdgcn_global_load_lds(
        (const __attribute__((address_space(1))) unsigned int*)g,
        (__attribute__((address_space(3))) unsigned int*)l, 16, 0, 0);
}
// swizzled byte offset into a [rows][256] bf16 LDS tile (chunk ^= row&7, low 3 bits)
__device__ __forceinline__ int swz(int row, int col) {
    return (row << 9) + ((((col >> 3) ^ (row & 7))) << 4) + ((col & 7) << 1);
}

__constant__ int NODE_OFF[9]  = {0, 119, 124, 136, 148, 158, 164, 170, 172};
__constant__ int NODE_MAXC[9] = {118, 4, 11, 11, 9, 5, 5, 1, 1};

// ---- transpose + bf16-cast the 21 256x256 weight matrices (LDS-tiled) ----
__global__ __launch_bounds__(256) void k_prep_weights(
    const float* __restrict__ W1, const float* __restrict__ W2,
    const float* __restrict__ vW1, const float* __restrict__ vW2,
    const float* __restrict__ hW1, u16* __restrict__ Wt)
{
    __shared__ float lt[64][65];
    int mat = blockIdx.x >> 4;
    int tile = blockIdx.x & 15;
    int tr = (tile >> 2) * 64;
    int tc = (tile & 3) * 64;
    const float* src;
    if (mat < 5)       src = W1 + (size_t)mat * 65536;
    else if (mat < 10) src = W2 + (size_t)(mat - 5) * 65536;
    else if (mat < 15) src = vW1 + (size_t)(mat - 10) * 65536;
    else if (mat < 20) src = vW2 + (size_t)(mat - 15) * 65536;
    else               src = hW1;
    int tid = threadIdx.x;
#pragma unroll
    for (int r = 0; r < 4; ++r) {
        int k = (tid >> 4) + r * 16;
        int c = (tid & 15) * 4;
        float4 v = *(const float4*)&src[(size_t)(tr + k) * 256 + tc + c];
        lt[k][c + 0] = v.x; lt[k][c + 1] = v.y;
        lt[k][c + 2] = v.z; lt[k][c + 3] = v.w;
    }
    __syncthreads();
#pragma unroll
    for (int r = 0; r < 4; ++r) {
        int n = (tid >> 4) + r * 16;
        int k = (tid & 15) * 4;
        ushort4 o;
        o.x = f2bf(lt[k + 0][n]); o.y = f2bf(lt[k + 1][n]);
        o.z = f2bf(lt[k + 2][n]); o.w = f2bf(lt[k + 3][n]);
        *(ushort4*)&Wt[(size_t)mat * 65536 + (size_t)(tc + n) * 256 + tr + k] = o;
    }
}

// ---- fused setup: vn init + gsum zero | comb table | segment starts ----
__global__ __launch_bounds__(256) void k_misc(
    const float* __restrict__ eemb, const int* __restrict__ batch,
    const float* __restrict__ vn_emb,
    u16* __restrict__ comb, int* __restrict__ starts,
    float* __restrict__ vn, u16* __restrict__ vnbf, float* __restrict__ gsum)
{
    int b = blockIdx.x;
    if (b < 2048) {
        int i = b * 256 + threadIdx.x;
        float v = vn_emb[i & 255];
        vn[i] = v;
        vnbf[i] = f2bf(v);
        gsum[i] = 0.f;
    } else if (b < 2108) {
        int r = b - 2048, c = threadIdx.x;
        int a0 = r / 12, a1 = (r % 12) / 2, a2 = r & 1;
        comb[r * 256 + c] = f2bf(eemb[a0 * 256 + c] + eemb[(5 + a1) * 256 + c] +
                                 eemb[(11 + a2) * 256 + c]);
    } else {
        int g = (b - 2108) * 256 + threadIdx.x;
        if (g > NG) return;
        int lo = 0, hi = NN;
        while (lo < hi) {
            int mid = (lo + hi) >> 1;
            if (batch[mid] < g) lo = mid + 1; else hi = mid;
        }
        starts[g] = lo;
    }
}

// ---- node embedding -> bf16 h; also zero deg ----
__global__ __launch_bounds__(256) void k_embed(const int* __restrict__ x,
                                               const float* __restrict__ node_emb,
                                               u16* __restrict__ hbf,
                                               int* __restrict__ deg)
{
    int i = blockIdx.x * 4 + (threadIdx.x >> 6);
    if (i >= NN) return;
    if ((threadIdx.x & 63) == 0) deg[i] = 0;
    int c = (threadIdx.x & 63) * 4;
    float4 s = make_float4(0.f, 0.f, 0.f, 0.f);
#pragma unroll
    for (int f = 0; f < 9; ++f) {
        int xv = x[i * 9 + f];
        xv = xv < 0 ? 0 : (xv > NODE_MAXC[f] ? NODE_MAXC[f] : xv);
        const float4 t = *(const float4*)&node_emb[(size_t)(NODE_OFF[f] + xv) * 256 + c];
        s.x += t.x; s.y += t.y; s.z += t.z; s.w += t.w;
    }
    ushort4 o;
    o.x = f2bf(s.x); o.y = f2bf(s.y); o.z = f2bf(s.z); o.w = f2bf(s.w);
    *(ushort4*)&hbf[(size_t)i * 256 + c] = o;
}

// ---- CSR-bucket build: slots[d*CAP+p] = src | code<<17 ----
__global__ __launch_bounds__(256) void k_bucket(
    const int* __restrict__ src, const int* __restrict__ dst,
    const int* __restrict__ eattr, int* __restrict__ deg, u32* __restrict__ slots)
{
    int e = blockIdx.x * 256 + threadIdx.x;
    if (e >= NE) return;
    int a0 = eattr[e * 3 + 0]; a0 = a0 < 0 ? 0 : (a0 > 4 ? 4 : a0);
    int a1 = eattr[e * 3 + 1]; a1 = a1 < 0 ? 0 : (a1 > 5 ? 5 : a1);
    int a2 = eattr[e * 3 + 2]; a2 = a2 < 0 ? 0 : (a2 > 1 ? 1 : a2);
    u32 code = (u32)(a0 * 12 + a1 * 2 + a2);
    int d = dst[e];
    int p = atomicAdd(&deg[d], 1);
    if (p < CAP) slots[(size_t)d * CAP + p] = (u32)src[e] | (code << 17);
}

// ---- gather-aggregate: per-edge vn (edges are cross-graph!), XCD-swizzled grid ----
__global__ __launch_bounds__(256) void k_agg(
    const u16* __restrict__ hbf, const u16* __restrict__ vnbf,
    const int* __restrict__ batch, const u32* __restrict__ slots,
    const int* __restrict__ deg, const u16* __restrict__ comb,
    u16* __restrict__ Abf, const float* __restrict__ epsp)
{
    // bijective XCD swizzle (m204): nwg=7500, q=937, r=4
    const int nwg = NN / 8;
    const int q = nwg / 8, r = nwg % 8;
    int xcd = blockIdx.x % 8, idx = blockIdx.x / 8;
    int bid = (xcd < r ? xcd * (q + 1) : r * (q + 1) + (xcd - r) * q) + idx;

    const int wid = threadIdx.x >> 6, lane = threadIdx.x & 63;
    const int half = lane >> 5, l32 = lane & 31;
    const int d = bid * 8 + wid * 2 + half;
    const int c = l32 * 8;
    int nd = deg[d];
    nd = nd > CAP ? CAP : nd;

    const u32* sl = slots + (size_t)d * CAP;
    u32 sv_l = (l32 < nd) ? sl[l32] : 0u;
    int b_l = (l32 < nd) ? batch[sv_l & 0x1FFFFu] : 0;

    float acc[8] = {0.f, 0.f, 0.f, 0.f, 0.f, 0.f, 0.f, 0.f};
    for (int p = 0; p < nd; ++p) {
        int srcl = (lane & 32) | p;
        u32 sv = (u32)__shfl((int)sv_l, srcl);
        int b  = __shfl(b_l, srcl);
        int s  = (int)(sv & 0x1FFFFu);
        int code = (int)(sv >> 17);
        const uint4 hv = *(const uint4*)&hbf[(size_t)s * 256 + c];
        const uint4 vv = *(const uint4*)&vnbf[(size_t)b * 256 + c];
        const uint4 tv = *(const uint4*)&comb[(size_t)code * 256 + c];
        const u32* hw = (const u32*)&hv;
        const u32* vw = (const u32*)&vv;
        const u32* tw = (const u32*)&tv;
#pragma unroll
        for (int e = 0; e < 4; ++e) {
            acc[e * 2 + 0] += fmaxf(bflo(hw[e]) + bflo(vw[e]) + bflo(tw[e]), 0.f);
            acc[e * 2 + 1] += fmaxf(bfhi(hw[e]) + bfhi(vw[e]) + bfhi(tw[e]), 0.f);
        }
    }

    int bd = batch[d];
    float ep = 1.0f + *epsp;
    const uint4 hd = *(const uint4*)&hbf[(size_t)d * 256 + c];
    const uint4 vd = *(const uint4*)&vnbf[(size_t)bd * 256 + c];
    const u32* hw = (const u32*)&hd;
    const u32* vw = (const u32*)&vd;
    uint4 o;
    u32* op = (u32*)&o;
#pragma unroll
    for (int e = 0; e < 4; ++e) {
        float lo = (bflo(hw[e]) + bflo(vw[e])) * ep + acc[e * 2 + 0];
        float hi = (bfhi(hw[e]) + bfhi(vw[e])) * ep + acc[e * 2 + 1];
        op[e] = pack2bf(lo, hi);
    }
    *(uint4*)&Abf[(size_t)d * 256 + c] = o;
}

// ======== shared GEMM building blocks (64-row tile, 8 waves) ========
__device__ __forceinline__ void stageW(const u16* __restrict__ W, u16* Bl,
                                       int k0, int tid, int wid)
{
#pragma unroll
    for (int i = 0; i < 4; ++i) {
        int slot = i * 512 + tid;
        int row = slot >> 3, cch = slot & 7;
        int g = cch ^ (row & 7);
        gload_lds16((const char*)W + (size_t)row * 512 + (size_t)k0 * 2 + (g << 4),
                    (char*)Bl + ((i * 512 + wid * 64) << 4));
    }
}

__device__ __forceinline__ void gemm64(const u16* Tl, u16* Bl, const u16* __restrict__ W,
                                       f32x4 (&acc)[2][4], int wm, int wn,
                                       int lane, int tid, int wid)
{
    const int cl = lane & 15;
    for (int k0 = 0; k0 < 256; k0 += 64) {
        __syncthreads();
        stageW(W, Bl, k0, tid, wid);
        __syncthreads();
#pragma unroll
        for (int kw = 0; kw < 2; ++kw) {
            int q = kw * 4 + (lane >> 4);
            int qt = (k0 >> 3) + q;
            bf16x8 af[2], bfr[4];
#pragma unroll
            for (int t = 0; t < 2; ++t) {
                int ar = wm + t * 16 + cl;
                af[t] = __builtin_bit_cast(bf16x8,
                    *(const uint4*)((const char*)Tl + (ar << 9) + ((qt ^ (ar & 7)) << 4)));
            }
#pragma unroll
            for (int t = 0; t < 4; ++t) {
                int br = wn + t * 16 + cl;
                bfr[t] = __builtin_bit_cast(bf16x8,
                    *(const uint4*)((const char*)Bl + (br << 7) + ((q ^ (br & 7)) << 4)));
            }
#pragma unroll
            for (int i = 0; i < 2; ++i)
#pragma unroll
                for (int j = 0; j < 4; ++j)
                    acc[i][j] = __builtin_amdgcn_mfma_f32_16x16x32_bf16(af[i], bfr[j], acc[i][j], 0, 0, 0);
        }
    }
}

__device__ __forceinline__ void writeT(u16* Tl, const f32x4 (&acc)[2][4],
                                       const float* __restrict__ b1,
                                       int wm, int wn, int lane)
{
    const int cl = lane & 15, rg = lane >> 4;
#pragma unroll
    for (int j = 0; j < 4; ++j) {
        int col = wn + j * 16 + cl;
        float bv = b1[col];
#pragma unroll
        for (int i = 0; i < 2; ++i)
#pragma unroll
            for (int r = 0; r < 4; ++r) {
                int row = wm + i * 16 + rg * 4 + r;
                float v = fmaxf(acc[i][j][r] + bv, 0.f);
                *(u16*)((char*)Tl + swz(row, col)) = f2bf(v);
            }
    }
}

// ======== k_mlpP — BM=64, W staged per-BK64 (best-known mlp) ========
__global__ __launch_bounds__(512) void k_mlpP(
    const u16* __restrict__ Abf, u16* __restrict__ hnxt,
    const int* __restrict__ batch,
    const u16* __restrict__ W1t, const u16* __restrict__ W2t,
    const float* __restrict__ b1, const float* __restrict__ b2,
    const float* __restrict__ bng, const float* __restrict__ bnb,
    const float* __restrict__ bnm, const float* __restrict__ bnv,
    float* __restrict__ gsum)
{
    __shared__ __align__(16) u16 Bl[256 * 64];
    __shared__ __align__(16) u16 Tl[64 * 256];
    __shared__ int batchLds[64];
    const int m0 = blockIdx.x * 64;
    const int tid = threadIdx.x, lane = tid & 63, wid = tid >> 6;
    const int wm = (wid >> 2) * 32, wn = (wid & 3) * 64;
    const int cl = lane & 15, rg = lane >> 4;

    if (tid < 64) batchLds[tid] = (m0 + tid < NN) ? batch[m0 + tid] : -1;

#pragma unroll
    for (int i = 0; i < 4; ++i) {
        int slot = i * 512 + tid;
        int row = slot >> 5, cch = slot & 31;
        int g = cch ^ (row & 7);
        gload_lds16((const char*)Abf + (size_t)(m0 + row) * 512 + (g << 4),
                    (char*)Tl + ((i * 512 + wid * 64) << 4));
    }

    f32x4 acc1[2][4] = {};
    gemm64(Tl, Bl, W1t, acc1, wm, wn, lane, tid, wid);
    __syncthreads();
    writeT(Tl, acc1, b1, wm, wn, lane);

    f32x4 acc2[2][4] = {};
    gemm64(Tl, Bl, W2t, acc2, wm, wn, lane, tid, wid);
    __syncthreads();

#pragma unroll
    for (int j = 0; j < 4; ++j) {
        int gn = wn + j * 16 + cl;
        float bv = b2[gn];
        float sc = bng[gn] * rsqrtf(bnv[gn] + 1e-5f);
        float sh = bnb[gn] - bnm[gn] * sc;
        float s = 0.f;
        int gcur = -1;
#pragma unroll
        for (int i = 0; i < 2; ++i) {
#pragma unroll
            for (int r = 0; r < 4; ++r) {
                int row = wm + i * 16 + rg * 4 + r;
                int g = batchLds[row];
                float v = acc2[i][j][r] + bv;
                u16 hb = f2bf(fmaxf(v * sc + sh, 0.f));
                if (g >= 0) hnxt[(size_t)(m0 + row) * 256 + gn] = hb;
                if (g != gcur) {
                    if (gcur >= 0) atomicAdd(&gsum[(size_t)gcur * 256 + gn], s);
                    gcur = g; s = 0.f;
                }
                if (g >= 0) s += bf2f(hb);
            }
        }
        if (gcur >= 0) atomicAdd(&gsum[(size_t)gcur * 256 + gn], s);
    }
}

// ======== fused pool-normalize + vn MLP (32 blocks x 64 graphs) ========
__global__ __launch_bounds__(512) void k_vnmlp(
    float* __restrict__ gsum, const int* __restrict__ starts,
    const u16* __restrict__ W1t, const u16* __restrict__ W2t,
    const float* __restrict__ b1, const float* __restrict__ b2,
    float* __restrict__ vn, u16* __restrict__ vnbf)
{
    __shared__ __align__(16) u16 Bl[256 * 64];
    __shared__ __align__(16) u16 Tl[64 * 256];
    const int m0 = blockIdx.x * 64;
    const int tid = threadIdx.x, lane = tid & 63, wid = tid >> 6;
    const int wm = (wid >> 2) * 32, wn = (wid & 3) * 64;
    const int cl = lane & 15, rg = lane >> 4;

    {
        const int c = lane * 4;
#pragma unroll
        for (int n = 0; n < 8; ++n) {
            int row = wid * 8 + n;
            int g = m0 + row;
            float4 sv = *(const float4*)&gsum[(size_t)g * 256 + c];
            *(float4*)&gsum[(size_t)g * 256 + c] = make_float4(0.f, 0.f, 0.f, 0.f);
            float cnt = (float)(starts[g + 1] - starts[g]);
            float inv = 1.0f / fmaxf(cnt, 1.0f);
            ushort4 o;
            o.x = f2bf(sv.x * inv); o.y = f2bf(sv.y * inv);
            o.z = f2bf(sv.z * inv); o.w = f2bf(sv.w * inv);
            *(ushort4*)((char*)Tl + swz(row, c)) = o;
        }
    }
    __syncthreads();

    f32x4 acc1[2][4] = {};
    gemm64(Tl, Bl, W1t, acc1, wm, wn, lane, tid, wid);
    __syncthreads();
    writeT(Tl, acc1, b1, wm, wn, lane);

    f32x4 acc2[2][4] = {};
    gemm64(Tl, Bl, W2t, acc2, wm, wn, lane, tid, wid);

#pragma unroll
    for (int j = 0; j < 4; ++j) {
        int gn = wn + j * 16 + cl;
        float bv = b2[gn];
#pragma unroll
        for (int i = 0; i < 2; ++i) {
#pragma unroll
            for (int r = 0; r < 4; ++r) {
                int gm = m0 + wm + i * 16 + rg * 4 + r;
                size_t idx = (size_t)gm * 256 + gn;
                float nv = vn[idx] + acc2[i][j][r] + bv;
                vn[idx] = nv;
                vnbf[idx] = f2bf(nv);
            }
        }
    }
}

// ======== fused head: pool-normalize -> relu(.@hW1+hb1) -> matvec hW2 ========
__global__ __launch_bounds__(512) void k_headf(
    const float* __restrict__ gsum, const int* __restrict__ starts,
    const u16* __restrict__ W1t, const float* __restrict__ b1,
    const float* __restrict__ hW2, const float* __restrict__ hb2,
    float* __restrict__ out)
{
    __shared__ __align__(16) u16 Bl[256 * 64];
    __shared__ __align__(16) u16 Tl[64 * 256];
    const int m0 = blockIdx.x * 64;
    const int tid = threadIdx.x, lane = tid & 63, wid = tid >> 6;
    const int wm = (wid >> 2) * 32, wn = (wid & 3) * 64;

    {
        const int c = lane * 4;
#pragma unroll
        for (int n = 0; n < 8; ++n) {
            int row = wid * 8 + n;
            int g = m0 + row;
            float4 sv = *(const float4*)&gsum[(size_t)g * 256 + c];
            float cnt = (float)(starts[g + 1] - starts[g]);
            float inv = 1.0f / fmaxf(cnt, 1.0f);
            ushort4 o;
            o.x = f2bf(sv.x * inv); o.y = f2bf(sv.y * inv);
            o.z = f2bf(sv.z * inv); o.w = f2bf(sv.w * inv);
            *(ushort4*)((char*)Tl + swz(row, c)) = o;
        }
    }
    __syncthreads();

    f32x4 acc1[2][4] = {};
    gemm64(Tl, Bl, W1t, acc1, wm, wn, lane, tid, wid);
    __syncthreads();
    writeT(Tl, acc1, b1, wm, wn, lane);
    __syncthreads();

    int row = tid >> 3, oct = tid & 7;
    float s = 0.f;
#pragma unroll
    for (int c = 0; c < 32; ++c) {
        int col = oct * 32 + c;
        s += bf2f(*(const u16*)((const char*)Tl + swz(row, col))) * hW2[col];
    }
    s += __shfl_down(s, 4);
    s += __shfl_down(s, 2);
    s += __shfl_down(s, 1);
    if (oct == 0) out[m0 + row] = s + hb2[0];
}

extern "C" void kernel_launch(void* const* d_in, const int* in_sizes, int n_in,
                              void* d_out, int out_size, void* d_ws, size_t ws_size,
                              hipStream_t stream)
{
    const int*   x        = (const int*)d_in[0];
    const int*   ei       = (const int*)d_in[1];
    const int*   eattr    = (const int*)d_in[2];
    const int*   batch    = (const int*)d_in[3];
    const float* node_emb = (const float*)d_in[4];
    const float* edge_emb = (const float*)d_in[5];
    const float* vn_emb   = (const float*)d_in[6];
    const float* eps      = (const float*)d_in[7];
    const float* W1       = (const float*)d_in[8];
    const float* b1       = (const float*)d_in[9];
    const float* W2       = (const float*)d_in[10];
    const float* b2       = (const float*)d_in[11];
    const float* bng      = (const float*)d_in[12];
    const float* bnb      = (const float*)d_in[13];
    const float* bnm      = (const float*)d_in[14];
    const float* bnv      = (const float*)d_in[15];
    const float* vW1      = (const float*)d_in[16];
    const float* vb1      = (const float*)d_in[17];
    const float* vW2      = (const float*)d_in[18];
    const float* vb2      = (const float*)d_in[19];
    const float* hW1      = (const float*)d_in[20];
    const float* hb1      = (const float*)d_in[21];
    const float* hW2      = (const float*)d_in[22];
    const float* hb2      = (const float*)d_in[23];
    float* out = (float*)d_out;

    char* ws = (char*)d_ws;
    size_t off = 0;
    auto alloc = [&](size_t b) {
        char* p = ws + off;
        off = (off + b + 255) & ~(size_t)255;
        return p;
    };
    u16*   hbf0 = (u16*)alloc((size_t)NN * 256 * 2);
    u16*   hbf1 = (u16*)alloc((size_t)NN * 256 * 2);
    u16*   Abf  = (u16*)alloc((size_t)NN * 256 * 2 + 65536);
    float* vn   = (float*)alloc((size_t)NG * 256 * 4);
    u16*   vnbf = (u16*)alloc((size_t)NG * 256 * 2);
    float* gsum = (float*)alloc((size_t)NG * 256 * 4);
    u16*   Wt   = (u16*)alloc((size_t)21 * 65536 * 2);
    int*   starts = (int*)alloc((size_t)(NG + 1) * 4);
    u16*   comb = (u16*)alloc((size_t)60 * 256 * 2);
    int*   deg  = (int*)alloc((size_t)NN * 4);
    u32*   slots = (u32*)alloc((size_t)NN * CAP * 4);

    const int* srcI = ei;
    const int* dstI = ei + NE;

    k_prep_weights<<<21 * 16, 256, 0, stream>>>(W1, W2, vW1, vW2, hW1, Wt);
    k_misc<<<2117, 256, 0, stream>>>(edge_emb, batch, vn_emb, comb, starts, vn, vnbf, gsum);
    k_embed<<<NN / 4, 256, 0, stream>>>(x, node_emb, hbf0, deg);
    k_bucket<<<(NE + 255) / 256, 256, 0, stream>>>(srcI, dstI, eattr, deg, slots);

    const int GBIG = (NN + 63) / 64;   // 938 blocks
    const int GSM  = NG / 64;          // 32 blocks

    u16* hcur = hbf0;
    u16* hnxt = hbf1;
    for (int l = 0; l < NL; ++l) {
        k_agg<<<NN / 8, 256, 0, stream>>>(hcur, vnbf, batch, slots, deg, comb, Abf, eps + l);
        k_mlpP<<<GBIG, 512, 0, stream>>>(Abf, hnxt, batch,
                                         Wt + (size_t)(0 + l) * 65536,
                                         Wt + (size_t)(5 + l) * 65536,
                                         b1 + l * 256, b2 + l * 256,
                                         bng + l * 256, bnb + l * 256,
                                         bnm + l * 256, bnv + l * 256,
                                         gsum);
        if (l < NL - 1) {
            k_vnmlp<<<GSM, 512, 0, stream>>>(gsum, starts,
                                             Wt + (size_t)(10 + l) * 65536,
                                             Wt + (size_t)(15 + l) * 65536,
                                             vb1 + l * 256, vb2 + l * 256,
                                             vn, vnbf);
        }
        u16* t = hcur; hcur = hnxt; hnxt = t;
    }
    k_headf<<<GSM, 512, 0, stream>>>(gsum, starts, Wt + (size_t)20 * 65536,
                                     hb1, hW2, hb2, out);
}

// Round 18
// 540.820 us; speedup vs baseline: 1.2223x; 1.0023x over previous
//
#include <hip/hip_runtime.h>

#define NN 60000
#define NE 180000
#define NG 2048
#define NL 5
#define CAP 32

typedef unsigned short u16;
typedef unsigned int u32;
typedef __bf16 bf16x8 __attribute__((ext_vector_type(8)));
typedef float f32x4 __attribute__((ext_vector_type(4)));

__device__ __forceinline__ u16 f2bf(float f) {
    u32 u = __builtin_bit_cast(u32, f);
    u += 0x7FFFu + ((u >> 16) & 1u);
    return (u16)(u >> 16);
}
__device__ __forceinline__ float bf2f(u16 s) {
    return __builtin_bit_cast(float, (u32)s << 16);
}
__device__ __forceinline__ float bflo(u32 w) {
    return __builtin_bit_cast(float, w << 16);
}
__device__ __forceinline__ float bfhi(u32 w) {
    return __builtin_bit_cast(float, w & 0xFFFF0000u);
}
__device__ __forceinline__ u32 pack2bf(float lo, float hi) {
    return (u32)f2bf(lo) | ((u32)f2bf(hi) << 16);
}
__device__ __forceinline__ void gload_lds16(const void* g, void* l) {
    __builtin_amdgcn_global_load_lds(
        (const __attribute__((address_space(1))) unsigned int*)g,
        (__attribute__((address_space(3))) unsigned int*)l, 16, 0, 0);
}
// swizzled byte offset into a [rows][256] bf16 LDS tile (chunk ^= row&7, low 3 bits)
__device__ __forceinline__ int swz(int row, int col) {
    return (row << 9) + ((((col >> 3) ^ (row & 7))) << 4) + ((col & 7) << 1);
}

__constant__ int NODE_OFF[9]  = {0, 119, 124, 136, 148, 158, 164, 170, 172};
__constant__ int NODE_MAXC[9] = {118, 4, 11, 11, 9, 5, 5, 1, 1};

// ---- transpose + bf16-cast the 21 256x256 weight matrices (LDS-tiled) ----
__global__ __launch_bounds__(256) void k_prep_weights(
    const float* __restrict__ W1, const float* __restrict__ W2,
    const float* __restrict__ vW1, const float* __restrict__ vW2,
    const float* __restrict__ hW1, u16* __restrict__ Wt)
{
    __shared__ float lt[64][65];
    int mat = blockIdx.x >> 4;
    int tile = blockIdx.x & 15;
    int tr = (tile >> 2) * 64;
    int tc = (tile & 3) * 64;
    const float* src;
    if (mat < 5)       src = W1 + (size_t)mat * 65536;
    else if (mat < 10) src = W2 + (size_t)(mat - 5) * 65536;
    else if (mat < 15) src = vW1 + (size_t)(mat - 10) * 65536;
    else if (mat < 20) src = vW2 + (size_t)(mat - 15) * 65536;
    else               src = hW1;
    int tid = threadIdx.x;
#pragma unroll
    for (int r = 0; r < 4; ++r) {
        int k = (tid >> 4) + r * 16;
        int c = (tid & 15) * 4;
        float4 v = *(const float4*)&src[(size_t)(tr + k) * 256 + tc + c];
        lt[k][c + 0] = v.x; lt[k][c + 1] = v.y;
        lt[k][c + 2] = v.z; lt[k][c + 3] = v.w;
    }
    __syncthreads();
#pragma unroll
    for (int r = 0; r < 4; ++r) {
        int n = (tid >> 4) + r * 16;
        int k = (tid & 15) * 4;
        ushort4 o;
        o.x = f2bf(lt[k + 0][n]); o.y = f2bf(lt[k + 1][n]);
        o.z = f2bf(lt[k + 2][n]); o.w = f2bf(lt[k + 3][n]);
        *(ushort4*)&Wt[(size_t)mat * 65536 + (size_t)(tc + n) * 256 + tr + k] = o;
    }
}

// ---- fused setup: vn init + gsum zero | comb table | segment starts ----
__global__ __launch_bounds__(256) void k_misc(
    const float* __restrict__ eemb, const int* __restrict__ batch,
    const float* __restrict__ vn_emb,
    u16* __restrict__ comb, int* __restrict__ starts,
    float* __restrict__ vn, u16* __restrict__ vnbf, float* __restrict__ gsum)
{
    int b = blockIdx.x;
    if (b < 2048) {
        int i = b * 256 + threadIdx.x;
        float v = vn_emb[i & 255];
        vn[i] = v;
        vnbf[i] = f2bf(v);
        gsum[i] = 0.f;
    } else if (b < 2108) {
        int r = b - 2048, c = threadIdx.x;
        int a0 = r / 12, a1 = (r % 12) / 2, a2 = r & 1;
        comb[r * 256 + c] = f2bf(eemb[a0 * 256 + c] + eemb[(5 + a1) * 256 + c] +
                                 eemb[(11 + a2) * 256 + c]);
    } else {
        int g = (b - 2108) * 256 + threadIdx.x;
        if (g > NG) return;
        int lo = 0, hi = NN;
        while (lo < hi) {
            int mid = (lo + hi) >> 1;
            if (batch[mid] < g) lo = mid + 1; else hi = mid;
        }
        starts[g] = lo;
    }
}

// ---- node embedding -> bf16 h; also zero deg ----
__global__ __launch_bounds__(256) void k_embed(const int* __restrict__ x,
                                               const float* __restrict__ node_emb,
                                               u16* __restrict__ hbf,
                                               int* __restrict__ deg)
{
    int i = blockIdx.x * 4 + (threadIdx.x >> 6);
    if (i >= NN) return;
    if ((threadIdx.x & 63) == 0) deg[i] = 0;
    int c = (threadIdx.x & 63) * 4;
    float4 s = make_float4(0.f, 0.f, 0.f, 0.f);
#pragma unroll
    for (int f = 0; f < 9; ++f) {
        int xv = x[i * 9 + f];
        xv = xv < 0 ? 0 : (xv > NODE_MAXC[f] ? NODE_MAXC[f] : xv);
        const float4 t = *(const float4*)&node_emb[(size_t)(NODE_OFF[f] + xv) * 256 + c];
        s.x += t.x; s.y += t.y; s.z += t.z; s.w += t.w;
    }
    ushort4 o;
    o.x = f2bf(s.x); o.y = f2bf(s.y); o.z = f2bf(s.z); o.w = f2bf(s.w);
    *(ushort4*)&hbf[(size_t)i * 256 + c] = o;
}

// ---- CSR-bucket build: slots[d*CAP+p] = src | code<<17 ----
__global__ __launch_bounds__(256) void k_bucket(
    const int* __restrict__ src, const int* __restrict__ dst,
    const int* __restrict__ eattr, int* __restrict__ deg, u32* __restrict__ slots)
{
    int e = blockIdx.x * 256 + threadIdx.x;
    if (e >= NE) return;
    int a0 = eattr[e * 3 + 0]; a0 = a0 < 0 ? 0 : (a0 > 4 ? 4 : a0);
    int a1 = eattr[e * 3 + 1]; a1 = a1 < 0 ? 0 : (a1 > 5 ? 5 : a1);
    int a2 = eattr[e * 3 + 2]; a2 = a2 < 0 ? 0 : (a2 > 1 ? 1 : a2);
    u32 code = (u32)(a0 * 12 + a1 * 2 + a2);
    int d = dst[e];
    int p = atomicAdd(&deg[d], 1);
    if (p < CAP) slots[(size_t)d * CAP + p] = (u32)src[e] | (code << 17);
}

// ---- gather-aggregate v3: 2x unrolled edge loop (uniform guard), XCD swizzle ----
__global__ __launch_bounds__(256) void k_agg(
    const u16* __restrict__ hbf, const u16* __restrict__ vnbf,
    const int* __restrict__ batch, const u32* __restrict__ slots,
    const int* __restrict__ deg, const u16* __restrict__ comb,
    u16* __restrict__ Abf, const float* __restrict__ epsp)
{
    // bijective XCD swizzle (m204): nwg=7500, q=937, r=4
    const int nwg = NN / 8;
    const int q = nwg / 8, r = nwg % 8;
    int xcd = blockIdx.x % 8, idx = blockIdx.x / 8;
    int bid = (xcd < r ? xcd * (q + 1) : r * (q + 1) + (xcd - r) * q) + idx;

    const int wid = threadIdx.x >> 6, lane = threadIdx.x & 63;
    const int half = lane >> 5, l32 = lane & 31;
    const int d = bid * 8 + wid * 2 + half;
    const int c = l32 * 8;
    int nd = deg[d];
    nd = nd > CAP ? CAP : nd;

    const u32* sl = slots + (size_t)d * CAP;
    u32 sv_l = (l32 < nd) ? sl[l32] : 0u;
    int b_l = (l32 < nd) ? batch[sv_l & 0x1FFFFu] : 0;

    float acc[8] = {0.f, 0.f, 0.f, 0.f, 0.f, 0.f, 0.f, 0.f};
    int p = 0;
    // 2x unrolled main loop: 6 independent loads issued per round.
    // nd is uniform across the half-wave -> guard is non-divergent.
    for (; p + 1 < nd; p += 2) {
        int sA = (lane & 32) | p;
        int sB = (lane & 32) | (p + 1);
        u32 svA = (u32)__shfl((int)sv_l, sA);
        u32 svB = (u32)__shfl((int)sv_l, sB);
        int bA = __shfl(b_l, sA);
        int bB = __shfl(b_l, sB);
        const uint4 hA = *(const uint4*)&hbf[(size_t)(svA & 0x1FFFFu) * 256 + c];
        const uint4 hB = *(const uint4*)&hbf[(size_t)(svB & 0x1FFFFu) * 256 + c];
        const uint4 vA = *(const uint4*)&vnbf[(size_t)bA * 256 + c];
        const uint4 vB = *(const uint4*)&vnbf[(size_t)bB * 256 + c];
        const uint4 tA = *(const uint4*)&comb[(size_t)(svA >> 17) * 256 + c];
        const uint4 tB = *(const uint4*)&comb[(size_t)(svB >> 17) * 256 + c];
        const u32* hwA = (const u32*)&hA; const u32* vwA = (const u32*)&vA;
        const u32* twA = (const u32*)&tA;
        const u32* hwB = (const u32*)&hB; const u32* vwB = (const u32*)&vB;
        const u32* twB = (const u32*)&tB;
#pragma unroll
        for (int e = 0; e < 4; ++e) {
            acc[e * 2 + 0] += fmaxf(bflo(hwA[e]) + bflo(vwA[e]) + bflo(twA[e]), 0.f);
            acc[e * 2 + 1] += fmaxf(bfhi(hwA[e]) + bfhi(vwA[e]) + bfhi(twA[e]), 0.f);
            acc[e * 2 + 0] += fmaxf(bflo(hwB[e]) + bflo(vwB[e]) + bflo(twB[e]), 0.f);
            acc[e * 2 + 1] += fmaxf(bfhi(hwB[e]) + bfhi(vwB[e]) + bfhi(twB[e]), 0.f);
        }
    }
    if (p < nd) {
        int sA = (lane & 32) | p;
        u32 sv = (u32)__shfl((int)sv_l, sA);
        int b  = __shfl(b_l, sA);
        const uint4 hv = *(const uint4*)&hbf[(size_t)(sv & 0x1FFFFu) * 256 + c];
        const uint4 vv = *(const uint4*)&vnbf[(size_t)b * 256 + c];
        const uint4 tv = *(const uint4*)&comb[(size_t)(sv >> 17) * 256 + c];
        const u32* hw = (const u32*)&hv;
        const u32* vw = (const u32*)&vv;
        const u32* tw = (const u32*)&tv;
#pragma unroll
        for (int e = 0; e < 4; ++e) {
            acc[e * 2 + 0] += fmaxf(bflo(hw[e]) + bflo(vw[e]) + bflo(tw[e]), 0.f);
            acc[e * 2 + 1] += fmaxf(bfhi(hw[e]) + bfhi(vw[e]) + bfhi(tw[e]), 0.f);
        }
    }

    int bd = batch[d];
    float ep = 1.0f + *epsp;
    const uint4 hd = *(const uint4*)&hbf[(size_t)d * 256 + c];
    const uint4 vd = *(const uint4*)&vnbf[(size_t)bd * 256 + c];
    const u32* hw = (const u32*)&hd;
    const u32* vw = (const u32*)&vd;
    uint4 o;
    u32* op = (u32*)&o;
#pragma unroll
    for (int e = 0; e < 4; ++e) {
        float lo = (bflo(hw[e]) + bflo(vw[e])) * ep + acc[e * 2 + 0];
        float hi = (bfhi(hw[e]) + bfhi(vw[e])) * ep + acc[e * 2 + 1];
        op[e] = pack2bf(lo, hi);
    }
    *(uint4*)&Abf[(size_t)d * 256 + c] = o;
}

// ======== shared GEMM building blocks (64-row tile, 8 waves) ========
__device__ __forceinline__ void stageW(const u16* __restrict__ W, u16* Bl,
                                       int k0, int tid, int wid)
{
#pragma unroll
    for (int i = 0; i < 4; ++i) {
        int slot = i * 512 + tid;
        int row = slot >> 3, cch = slot & 7;
        int g = cch ^ (row & 7);
        gload_lds16((const char*)W + (size_t)row * 512 + (size_t)k0 * 2 + (g << 4),
                    (char*)Bl + ((i * 512 + wid * 64) << 4));
    }
}

__device__ __forceinline__ void gemm64(const u16* Tl, u16* Bl, const u16* __restrict__ W,
                                       f32x4 (&acc)[2][4], int wm, int wn,
                                       int lane, int tid, int wid)
{
    const int cl = lane & 15;
    for (int k0 = 0; k0 < 256; k0 += 64) {
        __syncthreads();
        stageW(W, Bl, k0, tid, wid);
        __syncthreads();
#pragma unroll
        for (int kw = 0; kw < 2; ++kw) {
            int q = kw * 4 + (lane >> 4);
            int qt = (k0 >> 3) + q;
            bf16x8 af[2], bfr[4];
#pragma unroll
            for (int t = 0; t < 2; ++t) {
                int ar = wm + t * 16 + cl;
                af[t] = __builtin_bit_cast(bf16x8,
                    *(const uint4*)((const char*)Tl + (ar << 9) + ((qt ^ (ar & 7)) << 4)));
            }
#pragma unroll
            for (int t = 0; t < 4; ++t) {
                int br = wn + t * 16 + cl;
                bfr[t] = __builtin_bit_cast(bf16x8,
                    *(const uint4*)((const char*)Bl + (br << 7) + ((q ^ (br & 7)) << 4)));
            }
#pragma unroll
            for (int i = 0; i < 2; ++i)
#pragma unroll
                for (int j = 0; j < 4; ++j)
                    acc[i][j] = __builtin_amdgcn_mfma_f32_16x16x32_bf16(af[i], bfr[j], acc[i][j], 0, 0, 0);
        }
    }
}

__device__ __forceinline__ void writeT(u16* Tl, const f32x4 (&acc)[2][4],
                                       const float* __restrict__ b1,
                                       int wm, int wn, int lane)
{
    const int cl = lane & 15, rg = lane >> 4;
#pragma unroll
    for (int j = 0; j < 4; ++j) {
        int col = wn + j * 16 + cl;
        float bv = b1[col];
#pragma unroll
        for (int i = 0; i < 2; ++i)
#pragma unroll
            for (int r = 0; r < 4; ++r) {
                int row = wm + i * 16 + rg * 4 + r;
                float v = fmaxf(acc[i][j][r] + bv, 0.f);
                *(u16*)((char*)Tl + swz(row, col)) = f2bf(v);
            }
    }
}

// ======== k_mlpP — BM=64, W staged per-BK64 (best-known mlp) ========
__global__ __launch_bounds__(512) void k_mlpP(
    const u16* __restrict__ Abf, u16* __restrict__ hnxt,
    const int* __restrict__ batch,
    const u16* __restrict__ W1t, const u16* __restrict__ W2t,
    const float* __restrict__ b1, const float* __restrict__ b2,
    const float* __restrict__ bng, const float* __restrict__ bnb,
    const float* __restrict__ bnm, const float* __restrict__ bnv,
    float* __restrict__ gsum)
{
    __shared__ __align__(16) u16 Bl[256 * 64];
    __shared__ __align__(16) u16 Tl[64 * 256];
    __shared__ int batchLds[64];
    const int m0 = blockIdx.x * 64;
    const int tid = threadIdx.x, lane = tid & 63, wid = tid >> 6;
    const int wm = (wid >> 2) * 32, wn = (wid & 3) * 64;
    const int cl = lane & 15, rg = lane >> 4;

    if (tid < 64) batchLds[tid] = (m0 + tid < NN) ? batch[m0 + tid] : -1;

#pragma unroll
    for (int i = 0; i < 4; ++i) {
        int slot = i * 512 + tid;
        int row = slot >> 5, cch = slot & 31;
        int g = cch ^ (row & 7);
        gload_lds16((const char*)Abf + (size_t)(m0 + row) * 512 + (g << 4),
                    (char*)Tl + ((i * 512 + wid * 64) << 4));
    }

    f32x4 acc1[2][4] = {};
    gemm64(Tl, Bl, W1t, acc1, wm, wn, lane, tid, wid);
    __syncthreads();
    writeT(Tl, acc1, b1, wm, wn, lane);

    f32x4 acc2[2][4] = {};
    gemm64(Tl, Bl, W2t, acc2, wm, wn, lane, tid, wid);
    __syncthreads();

#pragma unroll
    for (int j = 0; j < 4; ++j) {
        int gn = wn + j * 16 + cl;
        float bv = b2[gn];
        float sc = bng[gn] * rsqrtf(bnv[gn] + 1e-5f);
        float sh = bnb[gn] - bnm[gn] * sc;
        float s = 0.f;
        int gcur = -1;
#pragma unroll
        for (int i = 0; i < 2; ++i) {
#pragma unroll
            for (int r = 0; r < 4; ++r) {
                int row = wm + i * 16 + rg * 4 + r;
                int g = batchLds[row];
                float v = acc2[i][j][r] + bv;
                u16 hb = f2bf(fmaxf(v * sc + sh, 0.f));
                if (g >= 0) hnxt[(size_t)(m0 + row) * 256 + gn] = hb;
                if (g != gcur) {
                    if (gcur >= 0) atomicAdd(&gsum[(size_t)gcur * 256 + gn], s);
                    gcur = g; s = 0.f;
                }
                if (g >= 0) s += bf2f(hb);
            }
        }
        if (gcur >= 0) atomicAdd(&gsum[(size_t)gcur * 256 + gn], s);
    }
}

// ======== fused pool-normalize + vn MLP (32 blocks x 64 graphs) ========
__global__ __launch_bounds__(512) void k_vnmlp(
    float* __restrict__ gsum, const int* __restrict__ starts,
    const u16* __restrict__ W1t, const u16* __restrict__ W2t,
    const float* __restrict__ b1, const float* __restrict__ b2,
    float* __restrict__ vn, u16* __restrict__ vnbf)
{
    __shared__ __align__(16) u16 Bl[256 * 64];
    __shared__ __align__(16) u16 Tl[64 * 256];
    const int m0 = blockIdx.x * 64;
    const int tid = threadIdx.x, lane = tid & 63, wid = tid >> 6;
    const int wm = (wid >> 2) * 32, wn = (wid & 3) * 64;
    const int cl = lane & 15, rg = lane >> 4;

    {
        const int c = lane * 4;
#pragma unroll
        for (int n = 0; n < 8; ++n) {
            int row = wid * 8 + n;
            int g = m0 + row;
            float4 sv = *(const float4*)&gsum[(size_t)g * 256 + c];
            *(float4*)&gsum[(size_t)g * 256 + c] = make_float4(0.f, 0.f, 0.f, 0.f);
            float cnt = (float)(starts[g + 1] - starts[g]);
            float inv = 1.0f / fmaxf(cnt, 1.0f);
            ushort4 o;
            o.x = f2bf(sv.x * inv); o.y = f2bf(sv.y * inv);
            o.z = f2bf(sv.z * inv); o.w = f2bf(sv.w * inv);
            *(ushort4*)((char*)Tl + swz(row, c)) = o;
        }
    }
    __syncthreads();

    f32x4 acc1[2][4] = {};
    gemm64(Tl, Bl, W1t, acc1, wm, wn, lane, tid, wid);
    __syncthreads();
    writeT(Tl, acc1, b1, wm, wn, lane);

    f32x4 acc2[2][4] = {};
    gemm64(Tl, Bl, W2t, acc2, wm, wn, lane, tid, wid);

#pragma unroll
    for (int j = 0; j < 4; ++j) {
        int gn = wn + j * 16 + cl;
        float bv = b2[gn];
#pragma unroll
        for (int i = 0; i < 2; ++i) {
#pragma unroll
            for (int r = 0; r < 4; ++r) {
                int gm = m0 + wm + i * 16 + rg * 4 + r;
                size_t idx = (size_t)gm * 256 + gn;
                float nv = vn[idx] + acc2[i][j][r] + bv;
                vn[idx] = nv;
                vnbf[idx] = f2bf(nv);
            }
        }
    }
}

// ======== fused head: pool-normalize -> relu(.@hW1+hb1) -> matvec hW2 ========
__global__ __launch_bounds__(512) void k_headf(
    const float* __restrict__ gsum, const int* __restrict__ starts,
    const u16* __restrict__ W1t, const float* __restrict__ b1,
    const float* __restrict__ hW2, const float* __restrict__ hb2,
    float* __restrict__ out)
{
    __shared__ __align__(16) u16 Bl[256 * 64];
    __shared__ __align__(16) u16 Tl[64 * 256];
    const int m0 = blockIdx.x * 64;
    const int tid = threadIdx.x, lane = tid & 63, wid = tid >> 6;
    const int wm = (wid >> 2) * 32, wn = (wid & 3) * 64;

    {
        const int c = lane * 4;
#pragma unroll
        for (int n = 0; n < 8; ++n) {
            int row = wid * 8 + n;
            int g = m0 + row;
            float4 sv = *(const float4*)&gsum[(size_t)g * 256 + c];
            float cnt = (float)(starts[g + 1] - starts[g]);
            float inv = 1.0f / fmaxf(cnt, 1.0f);
            ushort4 o;
            o.x = f2bf(sv.x * inv); o.y = f2bf(sv.y * inv);
            o.z = f2bf(sv.z * inv); o.w = f2bf(sv.w * inv);
            *(ushort4*)((char*)Tl + swz(row, c)) = o;
        }
    }
    __syncthreads();

    f32x4 acc1[2][4] = {};
    gemm64(Tl, Bl, W1t, acc1, wm, wn, lane, tid, wid);
    __syncthreads();
    writeT(Tl, acc1, b1, wm, wn, lane);
    __syncthreads();

    int row = tid >> 3, oct = tid & 7;
    float s = 0.f;
#pragma unroll
    for (int c = 0; c < 32; ++c) {
        int col = oct * 32 + c;
        s += bf2f(*(const u16*)((const char*)Tl + swz(row, col))) * hW2[col];
    }
    s += __shfl_down(s, 4);
    s += __shfl_down(s, 2);
    s += __shfl_down(s, 1);
    if (oct == 0) out[m0 + row] = s + hb2[0];
}

extern "C" void kernel_launch(void* const* d_in, const int* in_sizes, int n_in,
                              void* d_out, int out_size, void* d_ws, size_t ws_size,
                              hipStream_t stream)
{
    const int*   x        = (const int*)d_in[0];
    const int*   ei       = (const int*)d_in[1];
    const int*   eattr    = (const int*)d_in[2];
    const int*   batch    = (const int*)d_in[3];
    const float* node_emb = (const float*)d_in[4];
    const float* edge_emb = (const float*)d_in[5];
    const float* vn_emb   = (const float*)d_in[6];
    const float* eps      = (const float*)d_in[7];
    const float* W1       = (const float*)d_in[8];
    const float* b1       = (const float*)d_in[9];
    const float* W2       = (const float*)d_in[10];
    const float* b2       = (const float*)d_in[11];
    const float* bng      = (const float*)d_in[12];
    const float* bnb      = (const float*)d_in[13];
    const float* bnm      = (const float*)d_in[14];
    const float* bnv      = (const float*)d_in[15];
    const float* vW1      = (const float*)d_in[16];
    const float* vb1      = (const float*)d_in[17];
    const float* vW2      = (const float*)d_in[18];
    const float* vb2      = (const float*)d_in[19];
    const float* hW1      = (const float*)d_in[20];
    const float* hb1      = (const float*)d_in[21];
    const float* hW2      = (const float*)d_in[22];
    const float* hb2      = (const float*)d_in[23];
    float* out = (float*)d_out;

    char* ws = (char*)d_ws;
    size_t off = 0;
    auto alloc = [&](size_t b) {
        char* p = ws + off;
        off = (off + b + 255) & ~(size_t)255;
        return p;
    };
    u16*   hbf0 = (u16*)alloc((size_t)NN * 256 * 2);
    u16*   hbf1 = (u16*)alloc((size_t)NN * 256 * 2);
    u16*   Abf  = (u16*)alloc((size_t)NN * 256 * 2 + 65536);
    float* vn   = (float*)alloc((size_t)NG * 256 * 4);
    u16*   vnbf = (u16*)alloc((size_t)NG * 256 * 2);
    float* gsum = (float*)alloc((size_t)NG * 256 * 4);
    u16*   Wt   = (u16*)alloc((size_t)21 * 65536 * 2);
    int*   starts = (int*)alloc((size_t)(NG + 1) * 4);
    u16*   comb = (u16*)alloc((size_t)60 * 256 * 2);
    int*   deg  = (int*)alloc((size_t)NN * 4);
    u32*   slots = (u32*)alloc((size_t)NN * CAP * 4);

    const int* srcI = ei;
    const int* dstI = ei + NE;

    k_prep_weights<<<21 * 16, 256, 0, stream>>>(W1, W2, vW1, vW2, hW1, Wt);
    k_misc<<<2117, 256, 0, stream>>>(edge_emb, batch, vn_emb, comb, starts, vn, vnbf, gsum);
    k_embed<<<NN / 4, 256, 0, stream>>>(x, node_emb, hbf0, deg);
    k_bucket<<<(NE + 255) / 256, 256, 0, stream>>>(srcI, dstI, eattr, deg, slots);

    const int GBIG = (NN + 63) / 64;   // 938 blocks
    const int GSM  = NG / 64;          // 32 blocks

    u16* hcur = hbf0;
    u16* hnxt = hbf1;
    for (int l = 0; l < NL; ++l) {
        k_agg<<<NN / 8, 256, 0, stream>>>(hcur, vnbf, batch, slots, deg, comb, Abf, eps + l);
        k_mlpP<<<GBIG, 512, 0, stream>>>(Abf, hnxt, batch,
                                         Wt + (size_t)(0 + l) * 65536,
                                         Wt + (size_t)(5 + l) * 65536,
                                         b1 + l * 256, b2 + l * 256,
                                         bng + l * 256, bnb + l * 256,
                                         bnm + l * 256, bnv + l * 256,
                                         gsum);
        if (l < NL - 1) {
            k_vnmlp<<<GSM, 512, 0, stream>>>(gsum, starts,
                                             Wt + (size_t)(10 + l) * 65536,
                                             Wt + (size_t)(15 + l) * 65536,
                                             vb1 + l * 256, vb2 + l * 256,
                                             vn, vnbf);
        }
        u16* t = hcur; hcur = hnxt; hnxt = t;
    }
    k_headf<<<GSM, 512, 0, stream>>>(gsum, starts, Wt + (size_t)20 * 65536,
                                     hb1, hW2, hb2, out);
}

// Round 19
// 530.494 us; speedup vs baseline: 1.2461x; 1.0195x over previous
//
#include <hip/hip_runtime.h>

#define NN 60000
#define NE 180000
#define NG 2048
#define NL 5
#define CAP 32

typedef unsigned short u16;
typedef unsigned int u32;
typedef __bf16 bf16x8 __attribute__((ext_vector_type(8)));
typedef float f32x4 __attribute__((ext_vector_type(4)));

__device__ __forceinline__ u16 f2bf(float f) {
    u32 u = __builtin_bit_cast(u32, f);
    u += 0x7FFFu + ((u >> 16) & 1u);
    return (u16)(u >> 16);
}
__device__ __forceinline__ float bf2f(u16 s) {
    return __builtin_bit_cast(float, (u32)s << 16);
}
__device__ __forceinline__ float bflo(u32 w) {
    return __builtin_bit_cast(float, w << 16);
}
__device__ __forceinline__ float bfhi(u32 w) {
    return __builtin_bit_cast(float, w & 0xFFFF0000u);
}
__device__ __forceinline__ u32 pack2bf(float lo, float hi) {
    return (u32)f2bf(lo) | ((u32)f2bf(hi) << 16);
}
__device__ __forceinline__ void gload_lds16(const void* g, void* l) {
    __builtin_amdgcn_global_load_lds(
        (const __attribute__((address_space(1))) unsigned int*)g,
        (__attribute__((address_space(3))) unsigned int*)l, 16, 0, 0);
}
// swizzled byte offset into a [rows][256] bf16 LDS tile (chunk ^= row&7, low 3 bits)
__device__ __forceinline__ int swz(int row, int col) {
    return (row << 9) + ((((col >> 3) ^ (row & 7))) << 4) + ((col & 7) << 1);
}

__constant__ int NODE_OFF[9]  = {0, 119, 124, 136, 148, 158, 164, 170, 172};
__constant__ int NODE_MAXC[9] = {118, 4, 11, 11, 9, 5, 5, 1, 1};

// ---- transpose + bf16-cast the 21 256x256 weight matrices (LDS-tiled) ----
__global__ __launch_bounds__(256) void k_prep_weights(
    const float* __restrict__ W1, const float* __restrict__ W2,
    const float* __restrict__ vW1, const float* __restrict__ vW2,
    const float* __restrict__ hW1, u16* __restrict__ Wt)
{
    __shared__ float lt[64][65];
    int mat = blockIdx.x >> 4;
    int tile = blockIdx.x & 15;
    int tr = (tile >> 2) * 64;
    int tc = (tile & 3) * 64;
    const float* src;
    if (mat < 5)       src = W1 + (size_t)mat * 65536;
    else if (mat < 10) src = W2 + (size_t)(mat - 5) * 65536;
    else if (mat < 15) src = vW1 + (size_t)(mat - 10) * 65536;
    else if (mat < 20) src = vW2 + (size_t)(mat - 15) * 65536;
    else               src = hW1;
    int tid = threadIdx.x;
#pragma unroll
    for (int r = 0; r < 4; ++r) {
        int k = (tid >> 4) + r * 16;
        int c = (tid & 15) * 4;
        float4 v = *(const float4*)&src[(size_t)(tr + k) * 256 + tc + c];
        lt[k][c + 0] = v.x; lt[k][c + 1] = v.y;
        lt[k][c + 2] = v.z; lt[k][c + 3] = v.w;
    }
    __syncthreads();
#pragma unroll
    for (int r = 0; r < 4; ++r) {
        int n = (tid >> 4) + r * 16;
        int k = (tid & 15) * 4;
        ushort4 o;
        o.x = f2bf(lt[k + 0][n]); o.y = f2bf(lt[k + 1][n]);
        o.z = f2bf(lt[k + 2][n]); o.w = f2bf(lt[k + 3][n]);
        *(ushort4*)&Wt[(size_t)mat * 65536 + (size_t)(tc + n) * 256 + tr + k] = o;
    }
}

// ---- fused setup: vn init + gsum zero | comb table | segment starts ----
__global__ __launch_bounds__(256) void k_misc(
    const float* __restrict__ eemb, const int* __restrict__ batch,
    const float* __restrict__ vn_emb,
    u16* __restrict__ comb, int* __restrict__ starts,
    float* __restrict__ vn, u16* __restrict__ vnbf, float* __restrict__ gsum)
{
    int b = blockIdx.x;
    if (b < 2048) {
        int i = b * 256 + threadIdx.x;
        float v = vn_emb[i & 255];
        vn[i] = v;
        vnbf[i] = f2bf(v);
        gsum[i] = 0.f;
    } else if (b < 2108) {
        int r = b - 2048, c = threadIdx.x;
        int a0 = r / 12, a1 = (r % 12) / 2, a2 = r & 1;
        comb[r * 256 + c] = f2bf(eemb[a0 * 256 + c] + eemb[(5 + a1) * 256 + c] +
                                 eemb[(11 + a2) * 256 + c]);
    } else {
        int g = (b - 2108) * 256 + threadIdx.x;
        if (g > NG) return;
        int lo = 0, hi = NN;
        while (lo < hi) {
            int mid = (lo + hi) >> 1;
            if (batch[mid] < g) lo = mid + 1; else hi = mid;
        }
        starts[g] = lo;
    }
}

// ---- node embedding -> bf16 h; also zero deg ----
__global__ __launch_bounds__(256) void k_embed(const int* __restrict__ x,
                                               const float* __restrict__ node_emb,
                                               u16* __restrict__ hbf,
                                               int* __restrict__ deg)
{
    int i = blockIdx.x * 4 + (threadIdx.x >> 6);
    if (i >= NN) return;
    if ((threadIdx.x & 63) == 0) deg[i] = 0;
    int c = (threadIdx.x & 63) * 4;
    float4 s = make_float4(0.f, 0.f, 0.f, 0.f);
#pragma unroll
    for (int f = 0; f < 9; ++f) {
        int xv = x[i * 9 + f];
        xv = xv < 0 ? 0 : (xv > NODE_MAXC[f] ? NODE_MAXC[f] : xv);
        const float4 t = *(const float4*)&node_emb[(size_t)(NODE_OFF[f] + xv) * 256 + c];
        s.x += t.x; s.y += t.y; s.z += t.z; s.w += t.w;
    }
    ushort4 o;
    o.x = f2bf(s.x); o.y = f2bf(s.y); o.z = f2bf(s.z); o.w = f2bf(s.w);
    *(ushort4*)&hbf[(size_t)i * 256 + c] = o;
}

// ---- CSR-bucket build: slots[d*CAP+p] = src | code<<17 ----
__global__ __launch_bounds__(256) void k_bucket(
    const int* __restrict__ src, const int* __restrict__ dst,
    const int* __restrict__ eattr, int* __restrict__ deg, u32* __restrict__ slots)
{
    int e = blockIdx.x * 256 + threadIdx.x;
    if (e >= NE) return;
    int a0 = eattr[e * 3 + 0]; a0 = a0 < 0 ? 0 : (a0 > 4 ? 4 : a0);
    int a1 = eattr[e * 3 + 1]; a1 = a1 < 0 ? 0 : (a1 > 5 ? 5 : a1);
    int a2 = eattr[e * 3 + 2]; a2 = a2 < 0 ? 0 : (a2 > 1 ? 1 : a2);
    u32 code = (u32)(a0 * 12 + a1 * 2 + a2);
    int d = dst[e];
    int p = atomicAdd(&deg[d], 1);
    if (p < CAP) slots[(size_t)d * CAP + p] = (u32)src[e] | (code << 17);
}

// ---- gather-aggregate v3: 2x unrolled edge loop (uniform guard), XCD swizzle ----
__global__ __launch_bounds__(256) void k_agg(
    const u16* __restrict__ hbf, const u16* __restrict__ vnbf,
    const int* __restrict__ batch, const u32* __restrict__ slots,
    const int* __restrict__ deg, const u16* __restrict__ comb,
    u16* __restrict__ Abf, const float* __restrict__ epsp)
{
    const int nwg = NN / 8;
    const int q = nwg / 8, r = nwg % 8;
    int xcd = blockIdx.x % 8, idx = blockIdx.x / 8;
    int bid = (xcd < r ? xcd * (q + 1) : r * (q + 1) + (xcd - r) * q) + idx;

    const int wid = threadIdx.x >> 6, lane = threadIdx.x & 63;
    const int half = lane >> 5, l32 = lane & 31;
    const int d = bid * 8 + wid * 2 + half;
    const int c = l32 * 8;
    int nd = deg[d];
    nd = nd > CAP ? CAP : nd;

    const u32* sl = slots + (size_t)d * CAP;
    u32 sv_l = (l32 < nd) ? sl[l32] : 0u;
    int b_l = (l32 < nd) ? batch[sv_l & 0x1FFFFu] : 0;

    float acc[8] = {0.f, 0.f, 0.f, 0.f, 0.f, 0.f, 0.f, 0.f};
    int p = 0;
    for (; p + 1 < nd; p += 2) {
        int sA = (lane & 32) | p;
        int sB = (lane & 32) | (p + 1);
        u32 svA = (u32)__shfl((int)sv_l, sA);
        u32 svB = (u32)__shfl((int)sv_l, sB);
        int bA = __shfl(b_l, sA);
        int bB = __shfl(b_l, sB);
        const uint4 hA = *(const uint4*)&hbf[(size_t)(svA & 0x1FFFFu) * 256 + c];
        const uint4 hB = *(const uint4*)&hbf[(size_t)(svB & 0x1FFFFu) * 256 + c];
        const uint4 vA = *(const uint4*)&vnbf[(size_t)bA * 256 + c];
        const uint4 vB = *(const uint4*)&vnbf[(size_t)bB * 256 + c];
        const uint4 tA = *(const uint4*)&comb[(size_t)(svA >> 17) * 256 + c];
        const uint4 tB = *(const uint4*)&comb[(size_t)(svB >> 17) * 256 + c];
        const u32* hwA = (const u32*)&hA; const u32* vwA = (const u32*)&vA;
        const u32* twA = (const u32*)&tA;
        const u32* hwB = (const u32*)&hB; const u32* vwB = (const u32*)&vB;
        const u32* twB = (const u32*)&tB;
#pragma unroll
        for (int e = 0; e < 4; ++e) {
            acc[e * 2 + 0] += fmaxf(bflo(hwA[e]) + bflo(vwA[e]) + bflo(twA[e]), 0.f);
            acc[e * 2 + 1] += fmaxf(bfhi(hwA[e]) + bfhi(vwA[e]) + bfhi(twA[e]), 0.f);
            acc[e * 2 + 0] += fmaxf(bflo(hwB[e]) + bflo(vwB[e]) + bflo(twB[e]), 0.f);
            acc[e * 2 + 1] += fmaxf(bfhi(hwB[e]) + bfhi(vwB[e]) + bfhi(twB[e]), 0.f);
        }
    }
    if (p < nd) {
        int sA = (lane & 32) | p;
        u32 sv = (u32)__shfl((int)sv_l, sA);
        int b  = __shfl(b_l, sA);
        const uint4 hv = *(const uint4*)&hbf[(size_t)(sv & 0x1FFFFu) * 256 + c];
        const uint4 vv = *(const uint4*)&vnbf[(size_t)b * 256 + c];
        const uint4 tv = *(const uint4*)&comb[(size_t)(sv >> 17) * 256 + c];
        const u32* hw = (const u32*)&hv;
        const u32* vw = (const u32*)&vv;
        const u32* tw = (const u32*)&tv;
#pragma unroll
        for (int e = 0; e < 4; ++e) {
            acc[e * 2 + 0] += fmaxf(bflo(hw[e]) + bflo(vw[e]) + bflo(tw[e]), 0.f);
            acc[e * 2 + 1] += fmaxf(bfhi(hw[e]) + bfhi(vw[e]) + bfhi(tw[e]), 0.f);
        }
    }

    int bd = batch[d];
    float ep = 1.0f + *epsp;
    const uint4 hd = *(const uint4*)&hbf[(size_t)d * 256 + c];
    const uint4 vd = *(const uint4*)&vnbf[(size_t)bd * 256 + c];
    const u32* hw = (const u32*)&hd;
    const u32* vw = (const u32*)&vd;
    uint4 o;
    u32* op = (u32*)&o;
#pragma unroll
    for (int e = 0; e < 4; ++e) {
        float lo = (bflo(hw[e]) + bflo(vw[e])) * ep + acc[e * 2 + 0];
        float hi = (bfhi(hw[e]) + bfhi(vw[e])) * ep + acc[e * 2 + 1];
        op[e] = pack2bf(lo, hi);
    }
    *(uint4*)&Abf[(size_t)d * 256 + c] = o;
}

// ======== shared GEMM building blocks (64-row tile, 8 waves) ========
__device__ __forceinline__ void stageW(const u16* __restrict__ W, u16* Bl,
                                       int k0, int tid, int wid)
{
#pragma unroll
    for (int i = 0; i < 4; ++i) {
        int slot = i * 512 + tid;
        int row = slot >> 3, cch = slot & 7;
        int g = cch ^ (row & 7);
        gload_lds16((const char*)W + (size_t)row * 512 + (size_t)k0 * 2 + (g << 4),
                    (char*)Bl + ((i * 512 + wid * 64) << 4));
    }
}

__device__ __forceinline__ void gemm64(const u16* Tl, u16* Bl, const u16* __restrict__ W,
                                       f32x4 (&acc)[2][4], int wm, int wn,
                                       int lane, int tid, int wid)
{
    const int cl = lane & 15;
    for (int k0 = 0; k0 < 256; k0 += 64) {
        __syncthreads();
        stageW(W, Bl, k0, tid, wid);
        __syncthreads();
#pragma unroll
        for (int kw = 0; kw < 2; ++kw) {
            int q = kw * 4 + (lane >> 4);
            int qt = (k0 >> 3) + q;
            bf16x8 af[2], bfr[4];
#pragma unroll
            for (int t = 0; t < 2; ++t) {
                int ar = wm + t * 16 + cl;
                af[t] = __builtin_bit_cast(bf16x8,
                    *(const uint4*)((const char*)Tl + (ar << 9) + ((qt ^ (ar & 7)) << 4)));
            }
#pragma unroll
            for (int t = 0; t < 4; ++t) {
                int br = wn + t * 16 + cl;
                bfr[t] = __builtin_bit_cast(bf16x8,
                    *(const uint4*)((const char*)Bl + (br << 7) + ((q ^ (br & 7)) << 4)));
            }
#pragma unroll
            for (int i = 0; i < 2; ++i)
#pragma unroll
                for (int j = 0; j < 4; ++j)
                    acc[i][j] = __builtin_amdgcn_mfma_f32_16x16x32_bf16(af[i], bfr[j], acc[i][j], 0, 0, 0);
        }
    }
}

__device__ __forceinline__ void writeT(u16* Tl, const f32x4 (&acc)[2][4],
                                       const float* __restrict__ b1,
                                       int wm, int wn, int lane)
{
    const int cl = lane & 15, rg = lane >> 4;
#pragma unroll
    for (int j = 0; j < 4; ++j) {
        int col = wn + j * 16 + cl;
        float bv = b1[col];
#pragma unroll
        for (int i = 0; i < 2; ++i)
#pragma unroll
            for (int r = 0; r < 4; ++r) {
                int row = wm + i * 16 + rg * 4 + r;
                float v = fmaxf(acc[i][j][r] + bv, 0.f);
                *(u16*)((char*)Tl + swz(row, col)) = f2bf(v);
            }
    }
}

// ======== k_mlpP — BM=64, W staged per-BK64 (control) ========
__global__ __launch_bounds__(512) void k_mlpP(
    const u16* __restrict__ Abf, u16* __restrict__ hnxt,
    const int* __restrict__ batch,
    const u16* __restrict__ W1t, const u16* __restrict__ W2t,
    const float* __restrict__ b1, const float* __restrict__ b2,
    const float* __restrict__ bng, const float* __restrict__ bnb,
    const float* __restrict__ bnm, const float* __restrict__ bnv,
    float* __restrict__ gsum)
{
    __shared__ __align__(16) u16 Bl[256 * 64];
    __shared__ __align__(16) u16 Tl[64 * 256];
    __shared__ int batchLds[64];
    const int m0 = blockIdx.x * 64;
    const int tid = threadIdx.x, lane = tid & 63, wid = tid >> 6;
    const int wm = (wid >> 2) * 32, wn = (wid & 3) * 64;
    const int cl = lane & 15, rg = lane >> 4;

    if (tid < 64) batchLds[tid] = (m0 + tid < NN) ? batch[m0 + tid] : -1;

#pragma unroll
    for (int i = 0; i < 4; ++i) {
        int slot = i * 512 + tid;
        int row = slot >> 5, cch = slot & 31;
        int g = cch ^ (row & 7);
        gload_lds16((const char*)Abf + (size_t)(m0 + row) * 512 + (g << 4),
                    (char*)Tl + ((i * 512 + wid * 64) << 4));
    }

    f32x4 acc1[2][4] = {};
    gemm64(Tl, Bl, W1t, acc1, wm, wn, lane, tid, wid);
    __syncthreads();
    writeT(Tl, acc1, b1, wm, wn, lane);

    f32x4 acc2[2][4] = {};
    gemm64(Tl, Bl, W2t, acc2, wm, wn, lane, tid, wid);
    __syncthreads();

#pragma unroll
    for (int j = 0; j < 4; ++j) {
        int gn = wn + j * 16 + cl;
        float bv = b2[gn];
        float sc = bng[gn] * rsqrtf(bnv[gn] + 1e-5f);
        float sh = bnb[gn] - bnm[gn] * sc;
        float s = 0.f;
        int gcur = -1;
#pragma unroll
        for (int i = 0; i < 2; ++i) {
#pragma unroll
            for (int r = 0; r < 4; ++r) {
                int row = wm + i * 16 + rg * 4 + r;
                int g = batchLds[row];
                float v = acc2[i][j][r] + bv;
                u16 hb = f2bf(fmaxf(v * sc + sh, 0.f));
                if (g >= 0) hnxt[(size_t)(m0 + row) * 256 + gn] = hb;
                if (g != gcur) {
                    if (gcur >= 0) atomicAdd(&gsum[(size_t)gcur * 256 + gn], s);
                    gcur = g; s = 0.f;
                }
                if (g >= 0) s += bf2f(hb);
            }
        }
        if (gcur >= 0) atomicAdd(&gsum[(size_t)gcur * 256 + gn], s);
    }
}

// ======== k_mlpV — wave-private W staging, counted vmcnt, 3 barriers total ========
// Each wave owns 64 rows x 32 cols; W chunk = 32 cols x 32 K = 2 KB, double-buffered.
__device__ __forceinline__ void stageWV(const u16* __restrict__ W, char* wbuf,
                                        int p, int wn, int lane)
{
    // 2 gload_lds: slot = i*64 + lane; row = slot>>2 (0..31), cch = slot&3
#pragma unroll
    for (int i = 0; i < 2; ++i) {
        int slot = i * 64 + lane;
        int row = slot >> 2, cch = slot & 3;
        gload_lds16((const char*)W + (size_t)(wn + row) * 512 + p * 64 + (cch << 4),
                    wbuf + i * 1024);
    }
}

__device__ __forceinline__ void gemmV(f32x4 (&acc)[4][2], const u16* Tl,
                                      const u16* __restrict__ W,
                                      char* w0, char* w1,
                                      int wn, int cl, int rg, int lane)
{
#pragma unroll
    for (int p = 0; p < 8; ++p) {
        char* cur = (p & 1) ? w1 : w0;
        char* nxt = (p & 1) ? w0 : w1;
        if (p < 7) stageWV(W, nxt, p + 1, wn, lane);
        __builtin_amdgcn_sched_barrier(0);
        if (p < 7) { asm volatile("s_waitcnt vmcnt(2)" ::: "memory"); }
        else       { asm volatile("s_waitcnt vmcnt(0)" ::: "memory"); }
        __builtin_amdgcn_sched_barrier(0);
        int ch = p * 4 + rg;
        bf16x8 af[4], bfr[2];
#pragma unroll
        for (int i = 0; i < 4; ++i) {
            int ar = i * 16 + cl;
            af[i] = __builtin_bit_cast(bf16x8,
                *(const uint4*)((const char*)Tl + (ar << 9) + ((ch ^ (ar & 7)) << 4)));
        }
#pragma unroll
        for (int j = 0; j < 2; ++j) {
            int col = j * 16 + cl;
            bfr[j] = __builtin_bit_cast(bf16x8,
                *(const uint4*)(cur + col * 64 + rg * 16));
        }
#pragma unroll
        for (int i = 0; i < 4; ++i)
#pragma unroll
            for (int j = 0; j < 2; ++j)
                acc[i][j] = __builtin_amdgcn_mfma_f32_16x16x32_bf16(af[i], bfr[j], acc[i][j], 0, 0, 0);
    }
}

__global__ __launch_bounds__(512) void k_mlpV(
    const u16* __restrict__ Abf, u16* __restrict__ hnxt,
    const int* __restrict__ batch,
    const u16* __restrict__ W1t, const u16* __restrict__ W2t,
    const float* __restrict__ b1, const float* __restrict__ b2,
    const float* __restrict__ bng, const float* __restrict__ bnb,
    const float* __restrict__ bnm, const float* __restrict__ bnv,
    float* __restrict__ gsum)
{
    __shared__ __align__(16) u16 Tl[64 * 256];        // 32 KB
    __shared__ __align__(16) u16 Wb[8][2][32 * 32];   // 32 KB (2KB/wave/buf)
    __shared__ int batchLds[64];
    const int m0 = blockIdx.x * 64;
    const int tid = threadIdx.x, lane = tid & 63, wid = tid >> 6;
    const int wn = wid * 32;
    const int cl = lane & 15, rg = lane >> 4;

    if (tid < 64) batchLds[tid] = (m0 + tid < NN) ? batch[m0 + tid] : -1;

    // stage A (block-wide) + W1 chunk0 (wave-private); barrier drains both
#pragma unroll
    for (int i = 0; i < 4; ++i) {
        int slot = i * 512 + tid;
        int row = slot >> 5, cch = slot & 31;
        int g = cch ^ (row & 7);
        gload_lds16((const char*)Abf + (size_t)(m0 + row) * 512 + (g << 4),
                    (char*)Tl + ((i * 512 + wid * 64) << 4));
    }
    stageWV(W1t, (char*)Wb[wid][0], 0, wn, lane);
    __syncthreads();   // barrier 1

    f32x4 acc1[4][2] = {};
    gemmV(acc1, Tl, W1t, (char*)Wb[wid][0], (char*)Wb[wid][1], wn, cl, rg, lane);
    __syncthreads();   // barrier 2: all Tl(A) reads done

    stageWV(W2t, (char*)Wb[wid][0], 0, wn, lane);   // prefetch W2 chunk0
    // T = relu(acc1 + b1) -> Tl (swizzled)
#pragma unroll
    for (int j = 0; j < 2; ++j) {
        int col = wn + j * 16 + cl;
        float bv = b1[col];
#pragma unroll
        for (int i = 0; i < 4; ++i)
#pragma unroll
            for (int r = 0; r < 4; ++r) {
                int row = i * 16 + rg * 4 + r;
                float v = fmaxf(acc1[i][j][r] + bv, 0.f);
                *(u16*)((char*)Tl + swz(row, col)) = f2bf(v);
            }
    }
    __syncthreads();   // barrier 3: T ready; W2 chunk0 drained

    f32x4 acc2[4][2] = {};
    gemmV(acc2, Tl, W2t, (char*)Wb[wid][0], (char*)Wb[wid][1], wn, cl, rg, lane);

    // epilogue: h' = relu(BN(acc2+b2)); global write + in-register pool
#pragma unroll
    for (int j = 0; j < 2; ++j) {
        int gn = wn + j * 16 + cl;
        float bv = b2[gn];
        float sc = bng[gn] * rsqrtf(bnv[gn] + 1e-5f);
        float sh = bnb[gn] - bnm[gn] * sc;
        float s = 0.f;
        int gcur = -1;
#pragma unroll
        for (int i = 0; i < 4; ++i) {
#pragma unroll
            for (int r = 0; r < 4; ++r) {
                int row = i * 16 + rg * 4 + r;
                int g = batchLds[row];
                float v = acc2[i][j][r] + bv;
                u16 hb = f2bf(fmaxf(v * sc + sh, 0.f));
                if (g >= 0) hnxt[(size_t)(m0 + row) * 256 + gn] = hb;
                if (g != gcur) {
                    if (gcur >= 0) atomicAdd(&gsum[(size_t)gcur * 256 + gn], s);
                    gcur = g; s = 0.f;
                }
                if (g >= 0) s += bf2f(hb);
            }
        }
        if (gcur >= 0) atomicAdd(&gsum[(size_t)gcur * 256 + gn], s);
    }
}

// ======== fused pool-normalize + vn MLP (32 blocks x 64 graphs) ========
__global__ __launch_bounds__(512) void k_vnmlp(
    float* __restrict__ gsum, const int* __restrict__ starts,
    const u16* __restrict__ W1t, const u16* __restrict__ W2t,
    const float* __restrict__ b1, const float* __restrict__ b2,
    float* __restrict__ vn, u16* __restrict__ vnbf)
{
    __shared__ __align__(16) u16 Bl[256 * 64];
    __shared__ __align__(16) u16 Tl[64 * 256];
    const int m0 = blockIdx.x * 64;
    const int tid = threadIdx.x, lane = tid & 63, wid = tid >> 6;
    const int wm = (wid >> 2) * 32, wn = (wid & 3) * 64;
    const int cl = lane & 15, rg = lane >> 4;

    {
        const int c = lane * 4;
#pragma unroll
        for (int n = 0; n < 8; ++n) {
            int row = wid * 8 + n;
            int g = m0 + row;
            float4 sv = *(const float4*)&gsum[(size_t)g * 256 + c];
            *(float4*)&gsum[(size_t)g * 256 + c] = make_float4(0.f, 0.f, 0.f, 0.f);
            float cnt = (float)(starts[g + 1] - starts[g]);
            float inv = 1.0f / fmaxf(cnt, 1.0f);
            ushort4 o;
            o.x = f2bf(sv.x * inv); o.y = f2bf(sv.y * inv);
            o.z = f2bf(sv.z * inv); o.w = f2bf(sv.w * inv);
            *(ushort4*)((char*)Tl + swz(row, c)) = o;
        }
    }
    __syncthreads();

    f32x4 acc1[2][4] = {};
    gemm64(Tl, Bl, W1t, acc1, wm, wn, lane, tid, wid);
    __syncthreads();
    writeT(Tl, acc1, b1, wm, wn, lane);

    f32x4 acc2[2][4] = {};
    gemm64(Tl, Bl, W2t, acc2, wm, wn, lane, tid, wid);

#pragma unroll
    for (int j = 0; j < 4; ++j) {
        int gn = wn + j * 16 + cl;
        float bv = b2[gn];
#pragma unroll
        for (int i = 0; i < 2; ++i) {
#pragma unroll
            for (int r = 0; r < 4; ++r) {
                int gm = m0 + wm + i * 16 + rg * 4 + r;
                size_t idx = (size_t)gm * 256 + gn;
                float nv = vn[idx] + acc2[i][j][r] + bv;
                vn[idx] = nv;
                vnbf[idx] = f2bf(nv);
            }
        }
    }
}

// ======== fused head: pool-normalize -> relu(.@hW1+hb1) -> matvec hW2 ========
__global__ __launch_bounds__(512) void k_headf(
    const float* __restrict__ gsum, const int* __restrict__ starts,
    const u16* __restrict__ W1t, const float* __restrict__ b1,
    const float* __restrict__ hW2, const float* __restrict__ hb2,
    float* __restrict__ out)
{
    __shared__ __align__(16) u16 Bl[256 * 64];
    __shared__ __align__(16) u16 Tl[64 * 256];
    const int m0 = blockIdx.x * 64;
    const int tid = threadIdx.x, lane = tid & 63, wid = tid >> 6;
    const int wm = (wid >> 2) * 32, wn = (wid & 3) * 64;

    {
        const int c = lane * 4;
#pragma unroll
        for (int n = 0; n < 8; ++n) {
            int row = wid * 8 + n;
            int g = m0 + row;
            float4 sv = *(const float4*)&gsum[(size_t)g * 256 + c];
            float cnt = (float)(starts[g + 1] - starts[g]);
            float inv = 1.0f / fmaxf(cnt, 1.0f);
            ushort4 o;
            o.x = f2bf(sv.x * inv); o.y = f2bf(sv.y * inv);
            o.z = f2bf(sv.z * inv); o.w = f2bf(sv.w * inv);
            *(ushort4*)((char*)Tl + swz(row, c)) = o;
        }
    }
    __syncthreads();

    f32x4 acc1[2][4] = {};
    gemm64(Tl, Bl, W1t, acc1, wm, wn, lane, tid, wid);
    __syncthreads();
    writeT(Tl, acc1, b1, wm, wn, lane);
    __syncthreads();

    int row = tid >> 3, oct = tid & 7;
    float s = 0.f;
#pragma unroll
    for (int c = 0; c < 32; ++c) {
        int col = oct * 32 + c;
        s += bf2f(*(const u16*)((const char*)Tl + swz(row, col))) * hW2[col];
    }
    s += __shfl_down(s, 4);
    s += __shfl_down(s, 2);
    s += __shfl_down(s, 1);
    if (oct == 0) out[m0 + row] = s + hb2[0];
}

extern "C" void kernel_launch(void* const* d_in, const int* in_sizes, int n_in,
                              void* d_out, int out_size, void* d_ws, size_t ws_size,
                              hipStream_t stream)
{
    const int*   x        = (const int*)d_in[0];
    const int*   ei       = (const int*)d_in[1];
    const int*   eattr    = (const int*)d_in[2];
    const int*   batch    = (const int*)d_in[3];
    const float* node_emb = (const float*)d_in[4];
    const float* edge_emb = (const float*)d_in[5];
    const float* vn_emb   = (const float*)d_in[6];
    const float* eps      = (const float*)d_in[7];
    const float* W1       = (const float*)d_in[8];
    const float* b1       = (const float*)d_in[9];
    const float* W2       = (const float*)d_in[10];
    const float* b2       = (const float*)d_in[11];
    const float* bng      = (const float*)d_in[12];
    const float* bnb      = (const float*)d_in[13];
    const float* bnm      = (const float*)d_in[14];
    const float* bnv      = (const float*)d_in[15];
    const float* vW1      = (const float*)d_in[16];
    const float* vb1      = (const float*)d_in[17];
    const float* vW2      = (const float*)d_in[18];
    const float* vb2      = (const float*)d_in[19];
    const float* hW1      = (const float*)d_in[20];
    const float* hb1      = (const float*)d_in[21];
    const float* hW2      = (const float*)d_in[22];
    const float* hb2      = (const float*)d_in[23];
    float* out = (float*)d_out;

    char* ws = (char*)d_ws;
    size_t off = 0;
    auto alloc = [&](size_t b) {
        char* p = ws + off;
        off = (off + b + 255) & ~(size_t)255;
        return p;
    };
    u16*   hbf0 = (u16*)alloc((size_t)NN * 256 * 2);
    u16*   hbf1 = (u16*)alloc((size_t)NN * 256 * 2);
    u16*   Abf  = (u16*)alloc((size_t)NN * 256 * 2 + 65536);
    float* vn   = (float*)alloc((size_t)NG * 256 * 4);
    u16*   vnbf = (u16*)alloc((size_t)NG * 256 * 2);
    float* gsum = (float*)alloc((size_t)NG * 256 * 4);
    u16*   Wt   = (u16*)alloc((size_t)21 * 65536 * 2);
    int*   starts = (int*)alloc((size_t)(NG + 1) * 4);
    u16*   comb = (u16*)alloc((size_t)60 * 256 * 2);
    int*   deg  = (int*)alloc((size_t)NN * 4);
    u32*   slots = (u32*)alloc((size_t)NN * CAP * 4);

    const int* srcI = ei;
    const int* dstI = ei + NE;

    k_prep_weights<<<21 * 16, 256, 0, stream>>>(W1, W2, vW1, vW2, hW1, Wt);
    k_misc<<<2117, 256, 0, stream>>>(edge_emb, batch, vn_emb, comb, starts, vn, vnbf, gsum);
    k_embed<<<NN / 4, 256, 0, stream>>>(x, node_emb, hbf0, deg);
    k_bucket<<<(NE + 255) / 256, 256, 0, stream>>>(srcI, dstI, eattr, deg, slots);

    const int GBIG = (NN + 63) / 64;   // 938 blocks
    const int GSM  = NG / 64;          // 32 blocks

    u16* hcur = hbf0;
    u16* hnxt = hbf1;
    for (int l = 0; l < NL; ++l) {
        k_agg<<<NN / 8, 256, 0, stream>>>(hcur, vnbf, batch, slots, deg, comb, Abf, eps + l);
        const u16* w1p = Wt + (size_t)(0 + l) * 65536;
        const u16* w2p = Wt + (size_t)(5 + l) * 65536;
        if (l == 0 || l == 2 || l == 4) {
            k_mlpV<<<GBIG, 512, 0, stream>>>(Abf, hnxt, batch, w1p, w2p,
                                             b1 + l * 256, b2 + l * 256,
                                             bng + l * 256, bnb + l * 256,
                                             bnm + l * 256, bnv + l * 256, gsum);
        } else {
            k_mlpP<<<GBIG, 512, 0, stream>>>(Abf, hnxt, batch, w1p, w2p,
                                             b1 + l * 256, b2 + l * 256,
                                             bng + l * 256, bnb + l * 256,
                                             bnm + l * 256, bnv + l * 256, gsum);
        }
        if (l < NL - 1) {
            k_vnmlp<<<GSM, 512, 0, stream>>>(gsum, starts,
                                             Wt + (size_t)(10 + l) * 65536,
                                             Wt + (size_t)(15 + l) * 65536,
                                             vb1 + l * 256, vb2 + l * 256,
                                             vn, vnbf);
        }
        u16* t = hcur; hcur = hnxt; hnxt = t;
    }
    k_headf<<<GSM, 512, 0, stream>>>(gsum, starts, Wt + (size_t)20 * 65536,
                                     hb1, hW2, hb2, out);
}